// Round 10
// baseline (529.981 us; speedup 1.0000x reference)
//
#include <hip/hip_runtime.h>

#define N_NODES 100000
#define N_EDGES 1000000
#define IN_CH 166
#define HID 128
#define M_PAD 100032   // 1563 * 64
#define NTILE 1563
#define BSHIFT 9
#define NBUCK 196
#define BCAP 5632      // fixed bucket capacity (mean 5120, sd 72)

typedef unsigned short u16;
typedef unsigned int u32;
typedef __attribute__((ext_vector_type(8))) short short8;
typedef __attribute__((ext_vector_type(4))) float f32x4;

static __device__ __forceinline__ u16 f2bf(float f) {
    unsigned u = __float_as_uint(f);
    u += 0x7FFF + ((u >> 16) & 1);   // RNE
    return (u16)(u >> 16);
}
static __device__ __forceinline__ unsigned pk2(float a, float b) {
    return (unsigned)f2bf(a) | ((unsigned)f2bf(b) << 16);
}
static __device__ __forceinline__ float bf_lo(unsigned w) {
    return __uint_as_float(w << 16);
}
static __device__ __forceinline__ float bf_hi(unsigned w) {
    return __uint_as_float(w & 0xFFFF0000u);
}

// ================= graph build =================
// pass 1: scatter into fixed-capacity buckets (bucket = dst>>9)

__global__ __launch_bounds__(256) void k_scatter(const int* __restrict__ src,
                                                 const int* __restrict__ dst,
                                                 int* __restrict__ gcursor,
                                                 u32* __restrict__ stage) {
    __shared__ int cnt[NBUCK];
    __shared__ int base[NBUCK];
    const int t = threadIdx.x;
    if (t < NBUCK) cnt[t] = 0;
    __syncthreads();

    int4 s4[4], d4[4];
    bool ok[4];
#pragma unroll
    for (int j = 0; j < 4; ++j) {
        int e4 = blockIdx.x * 1024 + j * 256 + t;
        ok[j] = (e4 < N_EDGES / 4);
        if (ok[j]) {
            s4[j] = ((const int4*)src)[e4];
            d4[j] = ((const int4*)dst)[e4];
            atomicAdd(&cnt[d4[j].x >> BSHIFT], 1);
            atomicAdd(&cnt[d4[j].y >> BSHIFT], 1);
            atomicAdd(&cnt[d4[j].z >> BSHIFT], 1);
            atomicAdd(&cnt[d4[j].w >> BSHIFT], 1);
        }
    }
    __syncthreads();
    if (t < NBUCK && cnt[t] > 0) base[t] = atomicAdd(&gcursor[t], cnt[t]);
    __syncthreads();

#pragma unroll
    for (int j = 0; j < 4; ++j) {
        if (ok[j]) {
            const int ss[4] = {s4[j].x, s4[j].y, s4[j].z, s4[j].w};
            const int dd[4] = {d4[j].x, d4[j].y, d4[j].z, d4[j].w};
#pragma unroll
            for (int q = 0; q < 4; ++q) {
                int b = dd[q] >> BSHIFT;
                int r = atomicSub(&cnt[b], 1) - 1;
                stage[(size_t)b * BCAP + base[b] + r] =
                    ((u32)ss[q] << 9) | (u32)(dd[q] & 511);
            }
        }
    }
}

// pass 2: scan bucket counts (in gcursor after scatter) -> bucket_base
__global__ __launch_bounds__(256) void k_bucketscan(const int* __restrict__ gcursor,
                                                    int* __restrict__ bucket_base,
                                                    int* __restrict__ offsets) {
    __shared__ int ws[256];
    const int t = threadIdx.x;
    int loc = (t < NBUCK) ? gcursor[t] : 0;
    ws[t] = loc;
    __syncthreads();
    int val = loc;
    for (int stp = 1; stp < 256; stp <<= 1) {
        int other = (t >= stp) ? ws[t - stp] : 0;
        __syncthreads();
        val += other;
        ws[t] = val;
        __syncthreads();
    }
    if (t < NBUCK) bucket_base[t] = val - loc;
    if (t == 255) bucket_base[NBUCK] = val;
    if (t == 0) offsets[N_NODES] = N_EDGES;
}

// pass 3: per-bucket fine CSR
__global__ __launch_bounds__(256) void k_csr(const u32* __restrict__ stage,
                                             const int* __restrict__ bucket_base,
                                             int* __restrict__ offsets,
                                             int* __restrict__ ssrc) {
    __shared__ int cnt[512];
    __shared__ int ws[256];
    const int t = threadIdx.x;
    const int b = blockIdx.x;
    const int nb0 = b << BSHIFT;
    const int nn = min(512, N_NODES - nb0);
    const size_t e0s = (size_t)b * BCAP;
    const int e0 = bucket_base[b];
    const int m = bucket_base[b + 1] - e0;

    cnt[t] = 0;
    cnt[t + 256] = 0;
    __syncthreads();

    for (int i = t; i < m; i += 256) {
        u32 pr = stage[e0s + i];
        atomicAdd(&cnt[pr & 511], 1);
    }
    __syncthreads();

    int c0 = cnt[2 * t];
    int c1 = cnt[2 * t + 1];
    int loc = c0 + c1;
    ws[t] = loc;
    __syncthreads();
    int val = loc;
    for (int stp = 1; stp < 256; stp <<= 1) {
        int other = (t >= stp) ? ws[t - stp] : 0;
        __syncthreads();
        val += other;
        ws[t] = val;
        __syncthreads();
    }
    int p0 = e0 + (val - loc);
    int p1 = p0 + c0;
    if (2 * t < nn) offsets[nb0 + 2 * t] = p0;
    if (2 * t + 1 < nn) offsets[nb0 + 2 * t + 1] = p1;
    cnt[2 * t] = p0;
    cnt[2 * t + 1] = p1;
    __syncthreads();

    for (int i = t; i < m; i += 256) {
        u32 pr = stage[e0s + i];
        int p = atomicAdd(&cnt[pr & 511], 1);
        ssrc[p] = (int)(pr >> 9);
    }
}

// ---- degree-sorted node permutation (balances aggb wave divergence) ----

__global__ __launch_bounds__(256) void k_dhist(const int* __restrict__ offsets,
                                               int* __restrict__ dhist) {
    __shared__ int h[64];
    const int t = threadIdx.x;
    if (t < 64) h[t] = 0;
    __syncthreads();
    int n = blockIdx.x * 256 + t;
    if (n < N_NODES) {
        int deg = offsets[n + 1] - offsets[n];
        atomicAdd(&h[min(deg, 63)], 1);
    }
    __syncthreads();
    if (t < 64 && h[t] > 0) atomicAdd(&dhist[t], h[t]);
}

__global__ void k_dscan(const int* __restrict__ dhist, int* __restrict__ dcur) {
    __shared__ int s[64];
    const int t = threadIdx.x;   // 64 threads
    int v = dhist[t];
    s[t] = v;
    __syncthreads();
    int val = v;
    for (int stp = 1; stp < 64; stp <<= 1) {
        int other = (t >= stp) ? s[t - stp] : 0;
        __syncthreads();
        val += other;
        s[t] = val;
        __syncthreads();
    }
    dcur[t] = val - v;
}

__global__ __launch_bounds__(256) void k_dscatter(const int* __restrict__ offsets,
                                                  int* __restrict__ dcur,
                                                  int* __restrict__ perm) {
    int n = blockIdx.x * 256 + threadIdx.x;
    if (n < N_NODES) {
        int deg = offsets[n + 1] - offsets[n];
        int p = atomicAdd(&dcur[min(deg, 63)], 1);
        perm[p] = n;
    }
}

// ---------------- weight prep: Wl|Wr -> bf16 MFMA fragments ----------------

__global__ __launch_bounds__(64) void k_wprep(const float* __restrict__ Wl,
                                              const float* __restrict__ Wr,
                                              int Kact, u16* __restrict__ wf) {
    int lane = threadIdx.x;
    int kt = blockIdx.x >> 4;
    int ct = blockIdx.x & 15;
    int col = ct * 16 + (lane & 15);
    const float* W = (col < 128) ? Wl : Wr;
    int wcol = col & 127;
    float v[8];
#pragma unroll
    for (int j = 0; j < 8; ++j) {
        int row = kt * 32 + (lane >> 4) * 8 + j;
        v[j] = (row < Kact) ? W[(size_t)row * 128 + wcol] : 0.f;
    }
    int4 o;
    o.x = pk2(v[0], v[1]);
    o.y = pk2(v[2], v[3]);
    o.z = pk2(v[4], v[5]);
    o.w = pk2(v[6], v[7]);
    *(int4*)(wf + ((size_t)blockIdx.x * 64 + lane) * 8) = o;
}

// ---------------- MFMA projection with LDS-transpose epilogue ------------

#define STR2 136

template <int KP>
static __device__ __forceinline__ void proj_tail(const u16* __restrict__ wf,
                                                 const float* __restrict__ bias,
                                                 u16* __restrict__ y,
                                                 u16* __restrict__ rb,
                                                 u16* sA, int n0) {
    constexpr int STR = KP + 8;
    const int tid = threadIdx.x;
    const int wv = tid >> 6;
    const int lane = tid & 63;
    const int rg = wv & 1;
    const int cg = wv >> 1;
    const int r16 = lane & 15;
    const int kq = lane >> 4;

    f32x4 acc[2][4];
#pragma unroll
    for (int a = 0; a < 2; ++a)
#pragma unroll
        for (int b = 0; b < 4; ++b) acc[a][b] = (f32x4){0.f, 0.f, 0.f, 0.f};

#pragma unroll
    for (int kt = 0; kt < KP / 32; ++kt) {
        short8 af[2], bf[4];
#pragma unroll
        for (int rt = 0; rt < 2; ++rt)
            af[rt] = *(const short8*)(&sA[(rg * 32 + rt * 16 + r16) * STR + kt * 32 + kq * 8]);
#pragma unroll
        for (int c = 0; c < 4; ++c)
            bf[c] = *(const short8*)(wf + (((size_t)(kt * 16 + cg * 4 + c) * 64 + lane) * 8));
#pragma unroll
        for (int rt = 0; rt < 2; ++rt)
#pragma unroll
            for (int c = 0; c < 4; ++c)
                acc[rt][c] = __builtin_amdgcn_mfma_f32_16x16x32_bf16(bf[c], af[rt], acc[rt][c], 0, 0, 0);
    }

    // phase Y: cols 0..127 -> LDS -> coalesced int4 stores
    __syncthreads();
    if (cg < 2) {
#pragma unroll
        for (int rt = 0; rt < 2; ++rt) {
            int row = rg * 32 + rt * 16 + r16;
#pragma unroll
            for (int c = 0; c < 4; ++c) {
                int col = cg * 64 + c * 16 + kq * 4;
                int2 ov;
                ov.x = pk2(acc[rt][c][0], acc[rt][c][1]);
                ov.y = pk2(acc[rt][c][2], acc[rt][c][3]);
                *(int2*)(&sA[row * STR2 + col]) = ov;
            }
        }
    }
    __syncthreads();
#pragma unroll
    for (int p = 0; p < 2; ++p) {
        int c = p * 512 + tid;
        int row = c >> 4;
        int ch = c & 15;
        int4 v = *(const int4*)(&sA[row * STR2 + ch * 8]);
        *(int4*)(y + (size_t)(n0 + row) * 128 + ch * 8) = v;
    }
    // phase R: cols 128..255 (+bias)
    __syncthreads();
    if (cg >= 2) {
#pragma unroll
        for (int rt = 0; rt < 2; ++rt) {
            int row = rg * 32 + rt * 16 + r16;
#pragma unroll
            for (int c = 0; c < 4; ++c) {
                int col = (cg - 2) * 64 + c * 16 + kq * 4;
                float4 bv = *(const float4*)&bias[col];
                int2 ov;
                ov.x = pk2(acc[rt][c][0] + bv.x, acc[rt][c][1] + bv.y);
                ov.y = pk2(acc[rt][c][2] + bv.z, acc[rt][c][3] + bv.w);
                *(int2*)(&sA[row * STR2 + col]) = ov;
            }
        }
    }
    __syncthreads();
#pragma unroll
    for (int p = 0; p < 2; ++p) {
        int c = p * 512 + tid;
        int row = c >> 4;
        int ch = c & 15;
        int4 v = *(const int4*)(&sA[row * STR2 + ch * 8]);
        *(int4*)(rb + (size_t)(n0 + row) * 128 + ch * 8) = v;
    }
}

// layer 0: fp32 x [N,166]; tile = exactly 2656 aligned float4
__global__ __launch_bounds__(512, 4) void k_projmm0(const float* __restrict__ in,
                                                    const u16* __restrict__ wf,
                                                    const float* __restrict__ bias,
                                                    u16* __restrict__ y,
                                                    u16* __restrict__ rb) {
    constexpr int KP = 192;
    constexpr int STR = KP + 8;   // 200
    __shared__ u16 sA[64 * STR];
    const int tid = threadIdx.x;
    const int n0 = blockIdx.x * 64;

    // zero-fill K pad cols 166..191 (u32 writes: 13 per row)
    for (int c = tid; c < 64 * 13; c += 512) {
        int row = c / 13;
        int col = 166 + (c - row * 13) * 2;
        *(unsigned*)(&sA[row * STR + col]) = 0;
    }
    // zero-fill padding node rows of the last tile
    if (n0 + 63 >= N_NODES) {
        for (int c = tid; c < 64 * 83; c += 512) {
            int row = c / 83;
            if (n0 + row >= N_NODES)
                *(unsigned*)(&sA[row * STR + (c - row * 83) * 2]) = 0;
        }
    }
    // flat float4 staging: element e = f*4+j -> (row=e/166, k=e%166)
    const float4* x4 = (const float4*)in;
    const size_t gbase = (size_t)blockIdx.x * 2656;
#pragma unroll
    for (int it = 0; it < 6; ++it) {
        int f = it * 512 + tid;
        size_t gf = gbase + f;
        if (f < 2656 && gf < (size_t)N_NODES * IN_CH / 4) {
            float4 v = x4[gf];
            int e0 = f * 4;
            int row = e0 / IN_CH;
            int k = e0 - row * IN_CH;
            if (k <= IN_CH - 4) {   // fast path: all 4 in one row (97.6%)
                *(unsigned*)(&sA[row * STR + k]) = pk2(v.x, v.y);
                *(unsigned*)(&sA[row * STR + k + 2]) = pk2(v.z, v.w);
            } else {
                const float vv[4] = {v.x, v.y, v.z, v.w};
#pragma unroll
                for (int j = 0; j < 4; ++j) {
                    int kk = k + j;
                    int r = row, c = kk;
                    if (kk >= IN_CH) { r = row + 1; c = kk - IN_CH; }
                    sA[r * STR + c] = f2bf(vv[j]);
                }
            }
        }
    }
    __syncthreads();
    proj_tail<KP>(wf, bias, y, rb, sA, n0);
}

// layer 1: bf16 input [M_PAD,128]
__global__ __launch_bounds__(512, 4) void k_projmm1(const u16* __restrict__ in,
                                                    const u16* __restrict__ wf,
                                                    const float* __restrict__ bias,
                                                    u16* __restrict__ y,
                                                    u16* __restrict__ rb) {
    constexpr int KP = 128;
    constexpr int STR = KP + 8;
    __shared__ u16 sA[64 * STR];
    const int tid = threadIdx.x;
    const int n0 = blockIdx.x * 64;

#pragma unroll
    for (int it = 0; it < 2; ++it) {
        int c = it * 512 + tid;
        int row = c >> 4;
        int cc = c & 15;
        int4 v = *(const int4*)(in + (size_t)(n0 + row) * KP + cc * 8);
        *(int4*)(&sA[row * STR + cc * 8]) = v;
    }
    __syncthreads();
    proj_tail<KP>(wf, bias, y, rb, sA, n0);
}

// ---------------- aggregation (deg-sorted perm; optional fused layer-2) ---
// FUSE=0: h[node] = relu(mean_gather(yb) + rb)  (bf16 out)
// FUSE=1: additionally z[node] = h @ Wl2, r2[node] = h @ Wr2 + bl2 (fp32 h,
//         16-lane shfl reduce); h is NOT written.

template <int FUSE>
__global__ __launch_bounds__(256) void k_aggb(const u16* __restrict__ yb,
                                              const u16* __restrict__ rb,
                                              const int* __restrict__ offsets,
                                              const int* __restrict__ ssrc,
                                              const int* __restrict__ perm,
                                              u16* __restrict__ h,
                                              const float* __restrict__ Wl2,
                                              const float* __restrict__ Wr2,
                                              const float* __restrict__ bl2,
                                              float* __restrict__ z,
                                              float* __restrict__ r2) {
    __shared__ float2 sWl[128];
    __shared__ float2 sWr[128];
    const int tid = threadIdx.x;
    if (FUSE) {
        if (tid < 128) sWl[tid] = ((const float2*)Wl2)[tid];
        else sWr[tid - 128] = ((const float2*)Wr2)[tid - 128];
        __syncthreads();
    }
    const int lane = tid & 63;
    const int wv = tid >> 6;
    const int g = lane >> 4;
    const int i = lane & 15;
    const int node = perm[blockIdx.x * 16 + wv * 4 + g];
    const int off0 = offsets[node];
    const int deg = offsets[node + 1] - off0;

    float acc[8] = {0.f, 0.f, 0.f, 0.f, 0.f, 0.f, 0.f, 0.f};

    int e = 0;
    for (; e + 3 < deg; e += 4) {
        int s0 = ssrc[off0 + e];
        int s1 = ssrc[off0 + e + 1];
        int s2 = ssrc[off0 + e + 2];
        int s3 = ssrc[off0 + e + 3];
        int4 v0 = *(const int4*)(yb + (size_t)s0 * 128 + i * 8);
        int4 v1 = *(const int4*)(yb + (size_t)s1 * 128 + i * 8);
        int4 v2 = *(const int4*)(yb + (size_t)s2 * 128 + i * 8);
        int4 v3 = *(const int4*)(yb + (size_t)s3 * 128 + i * 8);
        const unsigned* w0 = (const unsigned*)&v0;
        const unsigned* w1 = (const unsigned*)&v1;
        const unsigned* w2 = (const unsigned*)&v2;
        const unsigned* w3 = (const unsigned*)&v3;
#pragma unroll
        for (int q = 0; q < 4; ++q) {
            acc[q * 2]     += (bf_lo(w0[q]) + bf_lo(w1[q])) + (bf_lo(w2[q]) + bf_lo(w3[q]));
            acc[q * 2 + 1] += (bf_hi(w0[q]) + bf_hi(w1[q])) + (bf_hi(w2[q]) + bf_hi(w3[q]));
        }
    }
    for (; e < deg; ++e) {
        int s0 = ssrc[off0 + e];
        int4 v0 = *(const int4*)(yb + (size_t)s0 * 128 + i * 8);
        const unsigned* w0 = (const unsigned*)&v0;
#pragma unroll
        for (int q = 0; q < 4; ++q) {
            acc[q * 2]     += bf_lo(w0[q]);
            acc[q * 2 + 1] += bf_hi(w0[q]);
        }
    }

    float inv = 1.f / (float)max(deg, 1);
    int4 rv = *(const int4*)(rb + (size_t)node * 128 + i * 8);
    const unsigned* rw = (const unsigned*)&rv;
    float o[8];
#pragma unroll
    for (int q = 0; q < 4; ++q) {
        o[q * 2]     = fmaxf(acc[q * 2] * inv + bf_lo(rw[q]), 0.f);
        o[q * 2 + 1] = fmaxf(acc[q * 2 + 1] * inv + bf_hi(rw[q]), 0.f);
    }

    if (!FUSE) {
        int4 ov;
        ov.x = pk2(o[0], o[1]);
        ov.y = pk2(o[2], o[3]);
        ov.z = pk2(o[4], o[5]);
        ov.w = pk2(o[6], o[7]);
        *(int4*)(h + (size_t)node * 128 + i * 8) = ov;
    } else {
        float zl0 = 0.f, zl1 = 0.f, zr0 = 0.f, zr1 = 0.f;
#pragma unroll
        for (int j = 0; j < 8; ++j) {
            float2 wl = sWl[i * 8 + j];
            float2 wr = sWr[i * 8 + j];
            zl0 += o[j] * wl.x;
            zl1 += o[j] * wl.y;
            zr0 += o[j] * wr.x;
            zr1 += o[j] * wr.y;
        }
#pragma unroll
        for (int d = 1; d < 16; d <<= 1) {
            zl0 += __shfl_xor(zl0, d);
            zl1 += __shfl_xor(zl1, d);
            zr0 += __shfl_xor(zr0, d);
            zr1 += __shfl_xor(zr1, d);
        }
        if (i == 0) {
            float2 zv; zv.x = zl0; zv.y = zl1;
            float2 rv2; rv2.x = zr0 + bl2[0]; rv2.y = zr1 + bl2[1];
            *(float2*)(z + (size_t)node * 2) = zv;
            *(float2*)(r2 + (size_t)node * 2) = rv2;
        }
    }
}

// ---------------- layer 2 aggregation (2 channels) ----------------

__global__ __launch_bounds__(256) void k_agg2(const float* __restrict__ z,
                                              const float* __restrict__ r2,
                                              const int* __restrict__ offsets,
                                              const int* __restrict__ ssrc,
                                              float* __restrict__ out) {
    int n = blockIdx.x * 256 + threadIdx.x;
    if (n >= N_NODES) return;
    int off0 = offsets[n];
    int off1 = offsets[n + 1];
    float a0 = 0.f, a1 = 0.f;
    for (int e = off0; e < off1; ++e) {
        int s = ssrc[e];
        a0 += z[s * 2];
        a1 += z[s * 2 + 1];
    }
    float inv = 1.0f / (float)max(off1 - off0, 1);
    out[n * 2 + 0] = a0 * inv + r2[n * 2 + 0];
    out[n * 2 + 1] = a1 * inv + r2[n * 2 + 1];
}

// ---------------- launcher ----------------

extern "C" void kernel_launch(void* const* d_in, const int* in_sizes, int n_in,
                              void* d_out, int out_size, void* d_ws, size_t ws_size,
                              hipStream_t stream) {
    const float* x   = (const float*)d_in[0];
    const int*   ei  = (const int*)d_in[1];
    const float* Wl0 = (const float*)d_in[2];
    const float* bl0 = (const float*)d_in[3];
    const float* Wr0 = (const float*)d_in[4];
    const float* Wl1 = (const float*)d_in[5];
    const float* bl1 = (const float*)d_in[6];
    const float* Wr1 = (const float*)d_in[7];
    const float* Wl2 = (const float*)d_in[8];
    const float* bl2 = (const float*)d_in[9];
    const float* Wr2 = (const float*)d_in[10];
    float* out = (float*)d_out;

    const int* srcp = ei;
    const int* dstp = ei + N_EDGES;

    char* ws = (char*)d_ws;
    size_t off = 0;
    auto alloc = [&](size_t bytes) -> void* {
        void* p = ws + off;
        off += (bytes + 255) & ~(size_t)255;
        return p;
    };
    int* gcursor     = (int*)alloc(NBUCK * 4);        // zeroed (with dhist)
    int* dhist       = (int*)alloc(64 * 4);
    int* bucket_base = (int*)alloc((NBUCK + 1) * 4);
    int* dcur        = (int*)alloc(64 * 4);
    int* offsets     = (int*)alloc((size_t)(N_NODES + 1) * 4);
    int* perm        = (int*)alloc((size_t)N_NODES * 4);
    u32* stage       = (u32*)alloc((size_t)NBUCK * BCAP * 4);
    int* ssrc        = (int*)alloc((size_t)N_EDGES * 4);
    u16* wf0         = (u16*)alloc((size_t)192 * 256 * 2);
    u16* wf1         = (u16*)alloc((size_t)128 * 256 * 2);
    u16* ybuf        = (u16*)alloc((size_t)M_PAD * 128 * 2);
    u16* rbuf        = (u16*)alloc((size_t)M_PAD * 128 * 2);
    u16* h0          = (u16*)alloc((size_t)M_PAD * 128 * 2);
    float* zbuf      = (float*)alloc((size_t)N_NODES * 2 * 4);
    float* r2buf     = (float*)alloc((size_t)N_NODES * 2 * 4);
    (void)ws_size; (void)n_in; (void)in_sizes; (void)out_size;

    // ---- graph build ----
    hipMemsetAsync(gcursor, 0, (NBUCK + 64 + 64) * 4 + 512, stream);  // gcursor+dhist (adjacent allocs)
    const int NB_SC = (N_EDGES / 4 + 1023) / 1024;   // 245
    k_scatter<<<NB_SC, 256, 0, stream>>>(srcp, dstp, gcursor, stage);
    k_bucketscan<<<1, 256, 0, stream>>>(gcursor, bucket_base, offsets);
    k_csr<<<NBUCK, 256, 0, stream>>>(stage, bucket_base, offsets, ssrc);

    // ---- degree-sorted node permutation ----
    const int NB_N = (N_NODES + 255) / 256;          // 391
    k_dhist<<<NB_N, 256, 0, stream>>>(offsets, dhist);
    k_dscan<<<1, 64, 0, stream>>>(dhist, dcur);
    k_dscatter<<<NB_N, 256, 0, stream>>>(offsets, dcur, perm);

    // ---- weight conversion ----
    k_wprep<<<(192 / 32) * 16, 64, 0, stream>>>(Wl0, Wr0, IN_CH, wf0);
    k_wprep<<<(128 / 32) * 16, 64, 0, stream>>>(Wl1, Wr1, HID, wf1);

    // ---- layer 0 ----
    k_projmm0<<<NTILE, 512, 0, stream>>>(x, wf0, bl0, ybuf, rbuf);
    k_aggb<0><<<N_NODES / 16, 256, 0, stream>>>(ybuf, rbuf, offsets, ssrc, perm,
                                                h0, nullptr, nullptr, nullptr,
                                                nullptr, nullptr);

    // ---- layer 1 (+ fused layer-2 projection) ----
    k_projmm1<<<NTILE, 512, 0, stream>>>(h0, wf1, bl1, ybuf, rbuf);
    k_aggb<1><<<N_NODES / 16, 256, 0, stream>>>(ybuf, rbuf, offsets, ssrc, perm,
                                                nullptr, Wl2, Wr2, bl2,
                                                zbuf, r2buf);

    // ---- layer 2 aggregation ----
    k_agg2<<<(N_NODES + 255) / 256, 256, 0, stream>>>(zbuf, r2buf, offsets, ssrc, out);
}

// Round 12
// 205.354 us; speedup vs baseline: 2.5808x; 2.5808x over previous
//
#include <hip/hip_runtime.h>

#define N_NODES 100000
#define N_EDGES 1000000
#define IN_CH 166
#define HID 128
#define M_PAD 100032   // 1563 * 64
#define NTILE 1563
#define BSHIFT 9
#define NBUCK 196
#define BCAP 5632      // fixed bucket capacity (mean 5120, sd 72)

typedef unsigned short u16;
typedef unsigned int u32;
typedef __attribute__((ext_vector_type(8))) short short8;
typedef __attribute__((ext_vector_type(4))) float f32x4;

static __device__ __forceinline__ u16 f2bf(float f) {
    unsigned u = __float_as_uint(f);
    u += 0x7FFF + ((u >> 16) & 1);   // RNE
    return (u16)(u >> 16);
}
static __device__ __forceinline__ unsigned pk2(float a, float b) {
    return (unsigned)f2bf(a) | ((unsigned)f2bf(b) << 16);
}
static __device__ __forceinline__ float bf_lo(unsigned w) {
    return __uint_as_float(w << 16);
}
static __device__ __forceinline__ float bf_hi(unsigned w) {
    return __uint_as_float(w & 0xFFFF0000u);
}

// ================= graph build =================
// pass 1: scatter into fixed-capacity buckets (bucket = dst>>9)

__global__ __launch_bounds__(256) void k_scatter(const int* __restrict__ src,
                                                 const int* __restrict__ dst,
                                                 int* __restrict__ gcursor,
                                                 u32* __restrict__ stage) {
    __shared__ int cnt[NBUCK];
    __shared__ int base[NBUCK];
    const int t = threadIdx.x;
    if (t < NBUCK) cnt[t] = 0;
    __syncthreads();

    int4 s4[4], d4[4];
    bool ok[4];
#pragma unroll
    for (int j = 0; j < 4; ++j) {
        int e4 = blockIdx.x * 1024 + j * 256 + t;
        ok[j] = (e4 < N_EDGES / 4);
        if (ok[j]) {
            s4[j] = ((const int4*)src)[e4];
            d4[j] = ((const int4*)dst)[e4];
            atomicAdd(&cnt[d4[j].x >> BSHIFT], 1);
            atomicAdd(&cnt[d4[j].y >> BSHIFT], 1);
            atomicAdd(&cnt[d4[j].z >> BSHIFT], 1);
            atomicAdd(&cnt[d4[j].w >> BSHIFT], 1);
        }
    }
    __syncthreads();
    if (t < NBUCK && cnt[t] > 0) base[t] = atomicAdd(&gcursor[t], cnt[t]);
    __syncthreads();

#pragma unroll
    for (int j = 0; j < 4; ++j) {
        if (ok[j]) {
            const int ss[4] = {s4[j].x, s4[j].y, s4[j].z, s4[j].w};
            const int dd[4] = {d4[j].x, d4[j].y, d4[j].z, d4[j].w};
#pragma unroll
            for (int q = 0; q < 4; ++q) {
                int b = dd[q] >> BSHIFT;
                int r = atomicSub(&cnt[b], 1) - 1;
                stage[(size_t)b * BCAP + base[b] + r] =
                    ((u32)ss[q] << 9) | (u32)(dd[q] & 511);
            }
        }
    }
}

// pass 2: scan bucket counts (in gcursor after scatter) -> bucket_base
__global__ __launch_bounds__(256) void k_bucketscan(const int* __restrict__ gcursor,
                                                    int* __restrict__ bucket_base,
                                                    int* __restrict__ offsets) {
    __shared__ int ws[256];
    const int t = threadIdx.x;
    int loc = (t < NBUCK) ? gcursor[t] : 0;
    ws[t] = loc;
    __syncthreads();
    int val = loc;
    for (int stp = 1; stp < 256; stp <<= 1) {
        int other = (t >= stp) ? ws[t - stp] : 0;
        __syncthreads();
        val += other;
        ws[t] = val;
        __syncthreads();
    }
    if (t < NBUCK) bucket_base[t] = val - loc;
    if (t == 255) bucket_base[NBUCK] = val;
    if (t == 0) offsets[N_NODES] = N_EDGES;
}

// pass 3: per-bucket fine CSR
__global__ __launch_bounds__(256) void k_csr(const u32* __restrict__ stage,
                                             const int* __restrict__ bucket_base,
                                             int* __restrict__ offsets,
                                             int* __restrict__ ssrc) {
    __shared__ int cnt[512];
    __shared__ int ws[256];
    const int t = threadIdx.x;
    const int b = blockIdx.x;
    const int nb0 = b << BSHIFT;
    const int nn = min(512, N_NODES - nb0);
    const size_t e0s = (size_t)b * BCAP;
    const int e0 = bucket_base[b];
    const int m = bucket_base[b + 1] - e0;

    cnt[t] = 0;
    cnt[t + 256] = 0;
    __syncthreads();

    for (int i = t; i < m; i += 256) {
        u32 pr = stage[e0s + i];
        atomicAdd(&cnt[pr & 511], 1);
    }
    __syncthreads();

    int c0 = cnt[2 * t];
    int c1 = cnt[2 * t + 1];
    int loc = c0 + c1;
    ws[t] = loc;
    __syncthreads();
    int val = loc;
    for (int stp = 1; stp < 256; stp <<= 1) {
        int other = (t >= stp) ? ws[t - stp] : 0;
        __syncthreads();
        val += other;
        ws[t] = val;
        __syncthreads();
    }
    int p0 = e0 + (val - loc);
    int p1 = p0 + c0;
    if (2 * t < nn) offsets[nb0 + 2 * t] = p0;
    if (2 * t + 1 < nn) offsets[nb0 + 2 * t + 1] = p1;
    cnt[2 * t] = p0;
    cnt[2 * t + 1] = p1;
    __syncthreads();

    for (int i = t; i < m; i += 256) {
        u32 pr = stage[e0s + i];
        int p = atomicAdd(&cnt[pr & 511], 1);
        ssrc[p] = (int)(pr >> 9);
    }
}

// ---- degree-sorted node permutation (two-level, low-contention) ----

__global__ __launch_bounds__(256) void k_dhist(const int* __restrict__ offsets,
                                               int* __restrict__ dhist) {
    __shared__ int h[64];
    const int t = threadIdx.x;
    if (t < 64) h[t] = 0;
    __syncthreads();
    int n = blockIdx.x * 256 + t;
    if (n < N_NODES) {
        int deg = offsets[n + 1] - offsets[n];
        atomicAdd(&h[min(deg, 63)], 1);
    }
    __syncthreads();
    if (t < 64 && h[t] > 0) atomicAdd(&dhist[t], h[t]);
}

__global__ void k_dscan(const int* __restrict__ dhist, int* __restrict__ dcur) {
    __shared__ int s[64];
    const int t = threadIdx.x;   // 64 threads
    int v = dhist[t];
    s[t] = v;
    __syncthreads();
    int val = v;
    for (int stp = 1; stp < 64; stp <<= 1) {
        int other = (t >= stp) ? s[t - stp] : 0;
        __syncthreads();
        val += other;
        s[t] = val;
        __syncthreads();
    }
    dcur[t] = val - v;
}

// two-level scatter: per-block LDS histogram -> 1 global atomic per bin/block
__global__ __launch_bounds__(256) void k_dscatter(const int* __restrict__ offsets,
                                                  int* __restrict__ dcur,
                                                  int* __restrict__ perm) {
    __shared__ int h[64];
    __shared__ int base[64];
    const int t = threadIdx.x;
    if (t < 64) h[t] = 0;
    __syncthreads();

    int n = blockIdx.x * 256 + t;
    int bin = -1;
    if (n < N_NODES) {
        int deg = offsets[n + 1] - offsets[n];
        bin = min(deg, 63);
        atomicAdd(&h[bin], 1);
    }
    __syncthreads();
    if (t < 64 && h[t] > 0) base[t] = atomicAdd(&dcur[t], h[t]);
    __syncthreads();
    if (bin >= 0) {
        int r = atomicSub(&h[bin], 1) - 1;
        perm[base[bin] + r] = n;
    }
}

// ---------------- weight prep: Wl|Wr -> bf16 MFMA fragments ----------------

__global__ __launch_bounds__(64) void k_wprep(const float* __restrict__ Wl,
                                              const float* __restrict__ Wr,
                                              int Kact, u16* __restrict__ wf) {
    int lane = threadIdx.x;
    int kt = blockIdx.x >> 4;
    int ct = blockIdx.x & 15;
    int col = ct * 16 + (lane & 15);
    const float* W = (col < 128) ? Wl : Wr;
    int wcol = col & 127;
    float v[8];
#pragma unroll
    for (int j = 0; j < 8; ++j) {
        int row = kt * 32 + (lane >> 4) * 8 + j;
        v[j] = (row < Kact) ? W[(size_t)row * 128 + wcol] : 0.f;
    }
    int4 o;
    o.x = pk2(v[0], v[1]);
    o.y = pk2(v[2], v[3]);
    o.z = pk2(v[4], v[5]);
    o.w = pk2(v[6], v[7]);
    *(int4*)(wf + ((size_t)blockIdx.x * 64 + lane) * 8) = o;
}

// ---------------- MFMA projection with LDS-transpose epilogue ------------

#define STR2 136

template <int KP>
static __device__ __forceinline__ void proj_tail(const u16* __restrict__ wf,
                                                 const float* __restrict__ bias,
                                                 u16* __restrict__ y,
                                                 u16* __restrict__ rb,
                                                 u16* sA, int n0) {
    constexpr int STR = KP + 8;
    const int tid = threadIdx.x;
    const int wv = tid >> 6;
    const int lane = tid & 63;
    const int rg = wv & 1;
    const int cg = wv >> 1;
    const int r16 = lane & 15;
    const int kq = lane >> 4;

    f32x4 acc[2][4];
#pragma unroll
    for (int a = 0; a < 2; ++a)
#pragma unroll
        for (int b = 0; b < 4; ++b) acc[a][b] = (f32x4){0.f, 0.f, 0.f, 0.f};

#pragma unroll
    for (int kt = 0; kt < KP / 32; ++kt) {
        short8 af[2], bf[4];
#pragma unroll
        for (int rt = 0; rt < 2; ++rt)
            af[rt] = *(const short8*)(&sA[(rg * 32 + rt * 16 + r16) * STR + kt * 32 + kq * 8]);
#pragma unroll
        for (int c = 0; c < 4; ++c)
            bf[c] = *(const short8*)(wf + (((size_t)(kt * 16 + cg * 4 + c) * 64 + lane) * 8));
#pragma unroll
        for (int rt = 0; rt < 2; ++rt)
#pragma unroll
            for (int c = 0; c < 4; ++c)
                acc[rt][c] = __builtin_amdgcn_mfma_f32_16x16x32_bf16(bf[c], af[rt], acc[rt][c], 0, 0, 0);
    }

    // phase Y: cols 0..127 -> LDS -> coalesced int4 stores
    __syncthreads();
    if (cg < 2) {
#pragma unroll
        for (int rt = 0; rt < 2; ++rt) {
            int row = rg * 32 + rt * 16 + r16;
#pragma unroll
            for (int c = 0; c < 4; ++c) {
                int col = cg * 64 + c * 16 + kq * 4;
                int2 ov;
                ov.x = pk2(acc[rt][c][0], acc[rt][c][1]);
                ov.y = pk2(acc[rt][c][2], acc[rt][c][3]);
                *(int2*)(&sA[row * STR2 + col]) = ov;
            }
        }
    }
    __syncthreads();
#pragma unroll
    for (int p = 0; p < 2; ++p) {
        int c = p * 512 + tid;
        int row = c >> 4;
        int ch = c & 15;
        int4 v = *(const int4*)(&sA[row * STR2 + ch * 8]);
        *(int4*)(y + (size_t)(n0 + row) * 128 + ch * 8) = v;
    }
    // phase R: cols 128..255 (+bias)
    __syncthreads();
    if (cg >= 2) {
#pragma unroll
        for (int rt = 0; rt < 2; ++rt) {
            int row = rg * 32 + rt * 16 + r16;
#pragma unroll
            for (int c = 0; c < 4; ++c) {
                int col = (cg - 2) * 64 + c * 16 + kq * 4;
                float4 bv = *(const float4*)&bias[col];
                int2 ov;
                ov.x = pk2(acc[rt][c][0] + bv.x, acc[rt][c][1] + bv.y);
                ov.y = pk2(acc[rt][c][2] + bv.z, acc[rt][c][3] + bv.w);
                *(int2*)(&sA[row * STR2 + col]) = ov;
            }
        }
    }
    __syncthreads();
#pragma unroll
    for (int p = 0; p < 2; ++p) {
        int c = p * 512 + tid;
        int row = c >> 4;
        int ch = c & 15;
        int4 v = *(const int4*)(&sA[row * STR2 + ch * 8]);
        *(int4*)(rb + (size_t)(n0 + row) * 128 + ch * 8) = v;
    }
}

// layer 0: fp32 x [N,166]; tile = exactly 2656 aligned float4
__global__ __launch_bounds__(512, 4) void k_projmm0(const float* __restrict__ in,
                                                    const u16* __restrict__ wf,
                                                    const float* __restrict__ bias,
                                                    u16* __restrict__ y,
                                                    u16* __restrict__ rb) {
    constexpr int KP = 192;
    constexpr int STR = KP + 8;   // 200
    __shared__ u16 sA[64 * STR];
    const int tid = threadIdx.x;
    const int n0 = blockIdx.x * 64;

    // zero-fill K pad cols 166..191 (u32 writes: 13 per row)
    for (int c = tid; c < 64 * 13; c += 512) {
        int row = c / 13;
        int col = 166 + (c - row * 13) * 2;
        *(unsigned*)(&sA[row * STR + col]) = 0;
    }
    // zero-fill padding node rows of the last tile
    if (n0 + 63 >= N_NODES) {
        for (int c = tid; c < 64 * 83; c += 512) {
            int row = c / 83;
            if (n0 + row >= N_NODES)
                *(unsigned*)(&sA[row * STR + (c - row * 83) * 2]) = 0;
        }
    }
    // flat float4 staging: element e = f*4+j -> (row=e/166, k=e%166)
    const float4* x4 = (const float4*)in;
    const size_t gbase = (size_t)blockIdx.x * 2656;
#pragma unroll
    for (int it = 0; it < 6; ++it) {
        int f = it * 512 + tid;
        size_t gf = gbase + f;
        if (f < 2656 && gf < (size_t)N_NODES * IN_CH / 4) {
            float4 v = x4[gf];
            int e0 = f * 4;
            int row = e0 / IN_CH;
            int k = e0 - row * IN_CH;
            if (k <= IN_CH - 4) {   // fast path: all 4 in one row (97.6%)
                *(unsigned*)(&sA[row * STR + k]) = pk2(v.x, v.y);
                *(unsigned*)(&sA[row * STR + k + 2]) = pk2(v.z, v.w);
            } else {
                const float vv[4] = {v.x, v.y, v.z, v.w};
#pragma unroll
                for (int j = 0; j < 4; ++j) {
                    int kk = k + j;
                    int r = row, c = kk;
                    if (kk >= IN_CH) { r = row + 1; c = kk - IN_CH; }
                    sA[r * STR + c] = f2bf(vv[j]);
                }
            }
        }
    }
    __syncthreads();
    proj_tail<KP>(wf, bias, y, rb, sA, n0);
}

// layer 1: bf16 input [M_PAD,128]
__global__ __launch_bounds__(512, 4) void k_projmm1(const u16* __restrict__ in,
                                                    const u16* __restrict__ wf,
                                                    const float* __restrict__ bias,
                                                    u16* __restrict__ y,
                                                    u16* __restrict__ rb) {
    constexpr int KP = 128;
    constexpr int STR = KP + 8;
    __shared__ u16 sA[64 * STR];
    const int tid = threadIdx.x;
    const int n0 = blockIdx.x * 64;

#pragma unroll
    for (int it = 0; it < 2; ++it) {
        int c = it * 512 + tid;
        int row = c >> 4;
        int cc = c & 15;
        int4 v = *(const int4*)(in + (size_t)(n0 + row) * KP + cc * 8);
        *(int4*)(&sA[row * STR + cc * 8]) = v;
    }
    __syncthreads();
    proj_tail<KP>(wf, bias, y, rb, sA, n0);
}

// ---------------- aggregation (deg-sorted perm; optional fused layer-2) ---

template <int FUSE>
__global__ __launch_bounds__(256) void k_aggb(const u16* __restrict__ yb,
                                              const u16* __restrict__ rb,
                                              const int* __restrict__ offsets,
                                              const int* __restrict__ ssrc,
                                              const int* __restrict__ perm,
                                              u16* __restrict__ h,
                                              const float* __restrict__ Wl2,
                                              const float* __restrict__ Wr2,
                                              const float* __restrict__ bl2,
                                              float* __restrict__ z,
                                              float* __restrict__ r2) {
    __shared__ float2 sWl[128];
    __shared__ float2 sWr[128];
    const int tid = threadIdx.x;
    if (FUSE) {
        if (tid < 128) sWl[tid] = ((const float2*)Wl2)[tid];
        else sWr[tid - 128] = ((const float2*)Wr2)[tid - 128];
        __syncthreads();
    }
    const int lane = tid & 63;
    const int wv = tid >> 6;
    const int g = lane >> 4;
    const int i = lane & 15;
    const int node = perm[blockIdx.x * 16 + wv * 4 + g];
    const int off0 = offsets[node];
    const int deg = offsets[node + 1] - off0;

    float acc[8] = {0.f, 0.f, 0.f, 0.f, 0.f, 0.f, 0.f, 0.f};

    int e = 0;
    for (; e + 3 < deg; e += 4) {
        int s0 = ssrc[off0 + e];
        int s1 = ssrc[off0 + e + 1];
        int s2 = ssrc[off0 + e + 2];
        int s3 = ssrc[off0 + e + 3];
        int4 v0 = *(const int4*)(yb + (size_t)s0 * 128 + i * 8);
        int4 v1 = *(const int4*)(yb + (size_t)s1 * 128 + i * 8);
        int4 v2 = *(const int4*)(yb + (size_t)s2 * 128 + i * 8);
        int4 v3 = *(const int4*)(yb + (size_t)s3 * 128 + i * 8);
        const unsigned* w0 = (const unsigned*)&v0;
        const unsigned* w1 = (const unsigned*)&v1;
        const unsigned* w2 = (const unsigned*)&v2;
        const unsigned* w3 = (const unsigned*)&v3;
#pragma unroll
        for (int q = 0; q < 4; ++q) {
            acc[q * 2]     += (bf_lo(w0[q]) + bf_lo(w1[q])) + (bf_lo(w2[q]) + bf_lo(w3[q]));
            acc[q * 2 + 1] += (bf_hi(w0[q]) + bf_hi(w1[q])) + (bf_hi(w2[q]) + bf_hi(w3[q]));
        }
    }
    for (; e < deg; ++e) {
        int s0 = ssrc[off0 + e];
        int4 v0 = *(const int4*)(yb + (size_t)s0 * 128 + i * 8);
        const unsigned* w0 = (const unsigned*)&v0;
#pragma unroll
        for (int q = 0; q < 4; ++q) {
            acc[q * 2]     += bf_lo(w0[q]);
            acc[q * 2 + 1] += bf_hi(w0[q]);
        }
    }

    float inv = 1.f / (float)max(deg, 1);
    int4 rv = *(const int4*)(rb + (size_t)node * 128 + i * 8);
    const unsigned* rw = (const unsigned*)&rv;
    float o[8];
#pragma unroll
    for (int q = 0; q < 4; ++q) {
        o[q * 2]     = fmaxf(acc[q * 2] * inv + bf_lo(rw[q]), 0.f);
        o[q * 2 + 1] = fmaxf(acc[q * 2 + 1] * inv + bf_hi(rw[q]), 0.f);
    }

    if (!FUSE) {
        int4 ov;
        ov.x = pk2(o[0], o[1]);
        ov.y = pk2(o[2], o[3]);
        ov.z = pk2(o[4], o[5]);
        ov.w = pk2(o[6], o[7]);
        *(int4*)(h + (size_t)node * 128 + i * 8) = ov;
    } else {
        float zl0 = 0.f, zl1 = 0.f, zr0 = 0.f, zr1 = 0.f;
#pragma unroll
        for (int j = 0; j < 8; ++j) {
            float2 wl = sWl[i * 8 + j];
            float2 wr = sWr[i * 8 + j];
            zl0 += o[j] * wl.x;
            zl1 += o[j] * wl.y;
            zr0 += o[j] * wr.x;
            zr1 += o[j] * wr.y;
        }
#pragma unroll
        for (int d = 1; d < 16; d <<= 1) {
            zl0 += __shfl_xor(zl0, d);
            zl1 += __shfl_xor(zl1, d);
            zr0 += __shfl_xor(zr0, d);
            zr1 += __shfl_xor(zr1, d);
        }
        if (i == 0) {
            float2 zv; zv.x = zl0; zv.y = zl1;
            float2 rv2; rv2.x = zr0 + bl2[0]; rv2.y = zr1 + bl2[1];
            *(float2*)(z + (size_t)node * 2) = zv;
            *(float2*)(r2 + (size_t)node * 2) = rv2;
        }
    }
}

// ---------------- layer 2 aggregation (2 channels) ----------------

__global__ __launch_bounds__(256) void k_agg2(const float* __restrict__ z,
                                              const float* __restrict__ r2,
                                              const int* __restrict__ offsets,
                                              const int* __restrict__ ssrc,
                                              float* __restrict__ out) {
    int n = blockIdx.x * 256 + threadIdx.x;
    if (n >= N_NODES) return;
    int off0 = offsets[n];
    int off1 = offsets[n + 1];
    float a0 = 0.f, a1 = 0.f;
    for (int e = off0; e < off1; ++e) {
        int s = ssrc[e];
        a0 += z[s * 2];
        a1 += z[s * 2 + 1];
    }
    float inv = 1.0f / (float)max(off1 - off0, 1);
    out[n * 2 + 0] = a0 * inv + r2[n * 2 + 0];
    out[n * 2 + 1] = a1 * inv + r2[n * 2 + 1];
}

// ---------------- launcher ----------------

extern "C" void kernel_launch(void* const* d_in, const int* in_sizes, int n_in,
                              void* d_out, int out_size, void* d_ws, size_t ws_size,
                              hipStream_t stream) {
    const float* x   = (const float*)d_in[0];
    const int*   ei  = (const int*)d_in[1];
    const float* Wl0 = (const float*)d_in[2];
    const float* bl0 = (const float*)d_in[3];
    const float* Wr0 = (const float*)d_in[4];
    const float* Wl1 = (const float*)d_in[5];
    const float* bl1 = (const float*)d_in[6];
    const float* Wr1 = (const float*)d_in[7];
    const float* Wl2 = (const float*)d_in[8];
    const float* bl2 = (const float*)d_in[9];
    const float* Wr2 = (const float*)d_in[10];
    float* out = (float*)d_out;

    const int* srcp = ei;
    const int* dstp = ei + N_EDGES;

    char* ws = (char*)d_ws;
    size_t off = 0;
    auto alloc = [&](size_t bytes) -> void* {
        void* p = ws + off;
        off += (bytes + 255) & ~(size_t)255;
        return p;
    };
    int* gcursor     = (int*)alloc(NBUCK * 4);        // offset 0    (pad to 1024)
    int* dhist       = (int*)alloc(64 * 4);           // offset 1024 (pad to 1280)
    int* bucket_base = (int*)alloc((NBUCK + 1) * 4);
    int* dcur        = (int*)alloc(64 * 4);
    int* offsets     = (int*)alloc((size_t)(N_NODES + 1) * 4);
    int* perm        = (int*)alloc((size_t)N_NODES * 4);
    u32* stage       = (u32*)alloc((size_t)NBUCK * BCAP * 4);
    int* ssrc        = (int*)alloc((size_t)N_EDGES * 4);
    u16* wf0         = (u16*)alloc((size_t)192 * 256 * 2);
    u16* wf1         = (u16*)alloc((size_t)128 * 256 * 2);
    u16* ybuf        = (u16*)alloc((size_t)M_PAD * 128 * 2);
    u16* rbuf        = (u16*)alloc((size_t)M_PAD * 128 * 2);
    u16* h0          = (u16*)alloc((size_t)M_PAD * 128 * 2);
    float* zbuf      = (float*)alloc((size_t)N_NODES * 2 * 4);
    float* r2buf     = (float*)alloc((size_t)N_NODES * 2 * 4);
    (void)ws_size; (void)n_in; (void)in_sizes; (void)out_size;

    // ---- graph build ----
    // zero gcursor (0..1023) AND dhist (1024..1279) — both are accumulated
    // into by atomics every call, so they must be re-zeroed per launch.
    hipMemsetAsync(gcursor, 0, 1280, stream);
    const int NB_SC = (N_EDGES / 4 + 1023) / 1024;   // 245
    k_scatter<<<NB_SC, 256, 0, stream>>>(srcp, dstp, gcursor, stage);
    k_bucketscan<<<1, 256, 0, stream>>>(gcursor, bucket_base, offsets);
    k_csr<<<NBUCK, 256, 0, stream>>>(stage, bucket_base, offsets, ssrc);

    // ---- degree-sorted node permutation (two-level) ----
    const int NB_N = (N_NODES + 255) / 256;          // 391
    k_dhist<<<NB_N, 256, 0, stream>>>(offsets, dhist);
    k_dscan<<<1, 64, 0, stream>>>(dhist, dcur);
    k_dscatter<<<NB_N, 256, 0, stream>>>(offsets, dcur, perm);

    // ---- weight conversion ----
    k_wprep<<<(192 / 32) * 16, 64, 0, stream>>>(Wl0, Wr0, IN_CH, wf0);
    k_wprep<<<(128 / 32) * 16, 64, 0, stream>>>(Wl1, Wr1, HID, wf1);

    // ---- layer 0 ----
    k_projmm0<<<NTILE, 512, 0, stream>>>(x, wf0, bl0, ybuf, rbuf);
    k_aggb<0><<<N_NODES / 16, 256, 0, stream>>>(ybuf, rbuf, offsets, ssrc, perm,
                                                h0, nullptr, nullptr, nullptr,
                                                nullptr, nullptr);

    // ---- layer 1 (+ fused layer-2 projection) ----
    k_projmm1<<<NTILE, 512, 0, stream>>>(h0, wf1, bl1, ybuf, rbuf);
    k_aggb<1><<<N_NODES / 16, 256, 0, stream>>>(ybuf, rbuf, offsets, ssrc, perm,
                                                nullptr, Wl2, Wr2, bl2,
                                                zbuf, r2buf);

    // ---- layer 2 aggregation ----
    k_agg2<<<(N_NODES + 255) / 256, 256, 0, stream>>>(zbuf, r2buf, offsets, ssrc, out);
}

// Round 13
// 188.571 us; speedup vs baseline: 2.8105x; 1.0890x over previous
//
#include <hip/hip_runtime.h>

#define N_NODES 100000
#define N_EDGES 1000000
#define IN_CH 166
#define HID 128
#define M_PAD 100032   // 1563 * 64
#define NTILE 1563
#define BSHIFT 9
#define NBUCK 196
#define BCAP 5632      // fixed bucket capacity (mean 5120, sd 72)

typedef unsigned short u16;
typedef unsigned int u32;
typedef __attribute__((ext_vector_type(8))) short short8;
typedef __attribute__((ext_vector_type(4))) float f32x4;

static __device__ __forceinline__ u16 f2bf(float f) {
    unsigned u = __float_as_uint(f);
    u += 0x7FFF + ((u >> 16) & 1);   // RNE
    return (u16)(u >> 16);
}
static __device__ __forceinline__ unsigned pk2(float a, float b) {
    return (unsigned)f2bf(a) | ((unsigned)f2bf(b) << 16);
}
static __device__ __forceinline__ float bf_lo(unsigned w) {
    return __uint_as_float(w << 16);
}
static __device__ __forceinline__ float bf_hi(unsigned w) {
    return __uint_as_float(w & 0xFFFF0000u);
}

// ================= graph build =================
// pass 1: scatter into fixed-capacity buckets (bucket = dst>>9)

__global__ __launch_bounds__(256) void k_scatter(const int* __restrict__ src,
                                                 const int* __restrict__ dst,
                                                 int* __restrict__ gcursor,
                                                 u32* __restrict__ stage) {
    __shared__ int cnt[NBUCK];
    __shared__ int base[NBUCK];
    const int t = threadIdx.x;
    if (t < NBUCK) cnt[t] = 0;
    __syncthreads();

    int4 s4[4], d4[4];
    bool ok[4];
#pragma unroll
    for (int j = 0; j < 4; ++j) {
        int e4 = blockIdx.x * 1024 + j * 256 + t;
        ok[j] = (e4 < N_EDGES / 4);
        if (ok[j]) {
            s4[j] = ((const int4*)src)[e4];
            d4[j] = ((const int4*)dst)[e4];
            atomicAdd(&cnt[d4[j].x >> BSHIFT], 1);
            atomicAdd(&cnt[d4[j].y >> BSHIFT], 1);
            atomicAdd(&cnt[d4[j].z >> BSHIFT], 1);
            atomicAdd(&cnt[d4[j].w >> BSHIFT], 1);
        }
    }
    __syncthreads();
    if (t < NBUCK && cnt[t] > 0) base[t] = atomicAdd(&gcursor[t], cnt[t]);
    __syncthreads();

#pragma unroll
    for (int j = 0; j < 4; ++j) {
        if (ok[j]) {
            const int ss[4] = {s4[j].x, s4[j].y, s4[j].z, s4[j].w};
            const int dd[4] = {d4[j].x, d4[j].y, d4[j].z, d4[j].w};
#pragma unroll
            for (int q = 0; q < 4; ++q) {
                int b = dd[q] >> BSHIFT;
                int r = atomicSub(&cnt[b], 1) - 1;
                stage[(size_t)b * BCAP + base[b] + r] =
                    ((u32)ss[q] << 9) | (u32)(dd[q] & 511);
            }
        }
    }
}

// pass 2: scan bucket counts (in gcursor after scatter) -> bucket_base
__global__ __launch_bounds__(256) void k_bucketscan(const int* __restrict__ gcursor,
                                                    int* __restrict__ bucket_base,
                                                    int* __restrict__ offsets) {
    __shared__ int ws[256];
    const int t = threadIdx.x;
    int loc = (t < NBUCK) ? gcursor[t] : 0;
    ws[t] = loc;
    __syncthreads();
    int val = loc;
    for (int stp = 1; stp < 256; stp <<= 1) {
        int other = (t >= stp) ? ws[t - stp] : 0;
        __syncthreads();
        val += other;
        ws[t] = val;
        __syncthreads();
    }
    if (t < NBUCK) bucket_base[t] = val - loc;
    if (t == 255) bucket_base[NBUCK] = val;
    if (t == 0) offsets[N_NODES] = N_EDGES;
}

// pass 3: per-bucket fine CSR
__global__ __launch_bounds__(256) void k_csr(const u32* __restrict__ stage,
                                             const int* __restrict__ bucket_base,
                                             int* __restrict__ offsets,
                                             int* __restrict__ ssrc) {
    __shared__ int cnt[512];
    __shared__ int ws[256];
    const int t = threadIdx.x;
    const int b = blockIdx.x;
    const int nb0 = b << BSHIFT;
    const int nn = min(512, N_NODES - nb0);
    const size_t e0s = (size_t)b * BCAP;
    const int e0 = bucket_base[b];
    const int m = bucket_base[b + 1] - e0;

    cnt[t] = 0;
    cnt[t + 256] = 0;
    __syncthreads();

    for (int i = t; i < m; i += 256) {
        u32 pr = stage[e0s + i];
        atomicAdd(&cnt[pr & 511], 1);
    }
    __syncthreads();

    int c0 = cnt[2 * t];
    int c1 = cnt[2 * t + 1];
    int loc = c0 + c1;
    ws[t] = loc;
    __syncthreads();
    int val = loc;
    for (int stp = 1; stp < 256; stp <<= 1) {
        int other = (t >= stp) ? ws[t - stp] : 0;
        __syncthreads();
        val += other;
        ws[t] = val;
        __syncthreads();
    }
    int p0 = e0 + (val - loc);
    int p1 = p0 + c0;
    if (2 * t < nn) offsets[nb0 + 2 * t] = p0;
    if (2 * t + 1 < nn) offsets[nb0 + 2 * t + 1] = p1;
    cnt[2 * t] = p0;
    cnt[2 * t + 1] = p1;
    __syncthreads();

    for (int i = t; i < m; i += 256) {
        u32 pr = stage[e0s + i];
        int p = atomicAdd(&cnt[pr & 511], 1);
        ssrc[p] = (int)(pr >> 9);
    }
}

// ---------------- weight prep: Wl|Wr -> bf16 MFMA fragments ----------------

__global__ __launch_bounds__(64) void k_wprep(const float* __restrict__ Wl,
                                              const float* __restrict__ Wr,
                                              int Kact, u16* __restrict__ wf) {
    int lane = threadIdx.x;
    int kt = blockIdx.x >> 4;
    int ct = blockIdx.x & 15;
    int col = ct * 16 + (lane & 15);
    const float* W = (col < 128) ? Wl : Wr;
    int wcol = col & 127;
    float v[8];
#pragma unroll
    for (int j = 0; j < 8; ++j) {
        int row = kt * 32 + (lane >> 4) * 8 + j;
        v[j] = (row < Kact) ? W[(size_t)row * 128 + wcol] : 0.f;
    }
    int4 o;
    o.x = pk2(v[0], v[1]);
    o.y = pk2(v[2], v[3]);
    o.z = pk2(v[4], v[5]);
    o.w = pk2(v[6], v[7]);
    *(int4*)(wf + ((size_t)blockIdx.x * 64 + lane) * 8) = o;
}

// ---------------- MFMA projection with LDS-transpose epilogue ------------

#define STR2 136

template <int KP>
static __device__ __forceinline__ void proj_tail(const u16* __restrict__ wf,
                                                 const float* __restrict__ bias,
                                                 u16* __restrict__ y,
                                                 u16* __restrict__ rb,
                                                 u16* sA, int n0) {
    constexpr int STR = KP + 8;
    const int tid = threadIdx.x;
    const int wv = tid >> 6;
    const int lane = tid & 63;
    const int rg = wv & 1;
    const int cg = wv >> 1;
    const int r16 = lane & 15;
    const int kq = lane >> 4;

    f32x4 acc[2][4];
#pragma unroll
    for (int a = 0; a < 2; ++a)
#pragma unroll
        for (int b = 0; b < 4; ++b) acc[a][b] = (f32x4){0.f, 0.f, 0.f, 0.f};

#pragma unroll
    for (int kt = 0; kt < KP / 32; ++kt) {
        short8 af[2], bf[4];
#pragma unroll
        for (int rt = 0; rt < 2; ++rt)
            af[rt] = *(const short8*)(&sA[(rg * 32 + rt * 16 + r16) * STR + kt * 32 + kq * 8]);
#pragma unroll
        for (int c = 0; c < 4; ++c)
            bf[c] = *(const short8*)(wf + (((size_t)(kt * 16 + cg * 4 + c) * 64 + lane) * 8));
#pragma unroll
        for (int rt = 0; rt < 2; ++rt)
#pragma unroll
            for (int c = 0; c < 4; ++c)
                acc[rt][c] = __builtin_amdgcn_mfma_f32_16x16x32_bf16(bf[c], af[rt], acc[rt][c], 0, 0, 0);
    }

    // phase Y: cols 0..127 -> LDS -> coalesced int4 stores
    __syncthreads();
    if (cg < 2) {
#pragma unroll
        for (int rt = 0; rt < 2; ++rt) {
            int row = rg * 32 + rt * 16 + r16;
#pragma unroll
            for (int c = 0; c < 4; ++c) {
                int col = cg * 64 + c * 16 + kq * 4;
                int2 ov;
                ov.x = pk2(acc[rt][c][0], acc[rt][c][1]);
                ov.y = pk2(acc[rt][c][2], acc[rt][c][3]);
                *(int2*)(&sA[row * STR2 + col]) = ov;
            }
        }
    }
    __syncthreads();
#pragma unroll
    for (int p = 0; p < 2; ++p) {
        int c = p * 512 + tid;
        int row = c >> 4;
        int ch = c & 15;
        int4 v = *(const int4*)(&sA[row * STR2 + ch * 8]);
        *(int4*)(y + (size_t)(n0 + row) * 128 + ch * 8) = v;
    }
    // phase R: cols 128..255 (+bias)
    __syncthreads();
    if (cg >= 2) {
#pragma unroll
        for (int rt = 0; rt < 2; ++rt) {
            int row = rg * 32 + rt * 16 + r16;
#pragma unroll
            for (int c = 0; c < 4; ++c) {
                int col = (cg - 2) * 64 + c * 16 + kq * 4;
                float4 bv = *(const float4*)&bias[col];
                int2 ov;
                ov.x = pk2(acc[rt][c][0] + bv.x, acc[rt][c][1] + bv.y);
                ov.y = pk2(acc[rt][c][2] + bv.z, acc[rt][c][3] + bv.w);
                *(int2*)(&sA[row * STR2 + col]) = ov;
            }
        }
    }
    __syncthreads();
#pragma unroll
    for (int p = 0; p < 2; ++p) {
        int c = p * 512 + tid;
        int row = c >> 4;
        int ch = c & 15;
        int4 v = *(const int4*)(&sA[row * STR2 + ch * 8]);
        *(int4*)(rb + (size_t)(n0 + row) * 128 + ch * 8) = v;
    }
}

// layer 0: fp32 x [N,166]; tile = exactly 2656 aligned float4
__global__ __launch_bounds__(512, 4) void k_projmm0(const float* __restrict__ in,
                                                    const u16* __restrict__ wf,
                                                    const float* __restrict__ bias,
                                                    u16* __restrict__ y,
                                                    u16* __restrict__ rb) {
    constexpr int KP = 192;
    constexpr int STR = KP + 8;   // 200
    __shared__ u16 sA[64 * STR];
    const int tid = threadIdx.x;
    const int n0 = blockIdx.x * 64;

    // zero-fill K pad cols 166..191 (u32 writes: 13 per row)
    for (int c = tid; c < 64 * 13; c += 512) {
        int row = c / 13;
        int col = 166 + (c - row * 13) * 2;
        *(unsigned*)(&sA[row * STR + col]) = 0;
    }
    // zero-fill padding node rows of the last tile
    if (n0 + 63 >= N_NODES) {
        for (int c = tid; c < 64 * 83; c += 512) {
            int row = c / 83;
            if (n0 + row >= N_NODES)
                *(unsigned*)(&sA[row * STR + (c - row * 83) * 2]) = 0;
        }
    }
    // flat float4 staging: element e = f*4+j -> (row=e/166, k=e%166)
    const float4* x4 = (const float4*)in;
    const size_t gbase = (size_t)blockIdx.x * 2656;
#pragma unroll
    for (int it = 0; it < 6; ++it) {
        int f = it * 512 + tid;
        size_t gf = gbase + f;
        if (f < 2656 && gf < (size_t)N_NODES * IN_CH / 4) {
            float4 v = x4[gf];
            int e0 = f * 4;
            int row = e0 / IN_CH;
            int k = e0 - row * IN_CH;
            if (k <= IN_CH - 4) {   // fast path: all 4 in one row (97.6%)
                *(unsigned*)(&sA[row * STR + k]) = pk2(v.x, v.y);
                *(unsigned*)(&sA[row * STR + k + 2]) = pk2(v.z, v.w);
            } else {
                const float vv[4] = {v.x, v.y, v.z, v.w};
#pragma unroll
                for (int j = 0; j < 4; ++j) {
                    int kk = k + j;
                    int r = row, c = kk;
                    if (kk >= IN_CH) { r = row + 1; c = kk - IN_CH; }
                    sA[r * STR + c] = f2bf(vv[j]);
                }
            }
        }
    }
    __syncthreads();
    proj_tail<KP>(wf, bias, y, rb, sA, n0);
}

// layer 1: bf16 input [M_PAD,128]
__global__ __launch_bounds__(512, 4) void k_projmm1(const u16* __restrict__ in,
                                                    const u16* __restrict__ wf,
                                                    const float* __restrict__ bias,
                                                    u16* __restrict__ y,
                                                    u16* __restrict__ rb) {
    constexpr int KP = 128;
    constexpr int STR = KP + 8;
    __shared__ u16 sA[64 * STR];
    const int tid = threadIdx.x;
    const int n0 = blockIdx.x * 64;

#pragma unroll
    for (int it = 0; it < 2; ++it) {
        int c = it * 512 + tid;
        int row = c >> 4;
        int cc = c & 15;
        int4 v = *(const int4*)(in + (size_t)(n0 + row) * KP + cc * 8);
        *(int4*)(&sA[row * STR + cc * 8]) = v;
    }
    __syncthreads();
    proj_tail<KP>(wf, bias, y, rb, sA, n0);
}

// ---------------- aggregation (identity order; optional fused layer-2) ---
// FUSE=0: h[node] = relu(mean_gather(yb) + rb)  (bf16 out)
// FUSE=1: additionally z[node] = h @ Wl2, r2[node] = h @ Wr2 + bl2; h not written.

template <int FUSE>
__global__ __launch_bounds__(256) void k_aggb(const u16* __restrict__ yb,
                                              const u16* __restrict__ rb,
                                              const int* __restrict__ offsets,
                                              const int* __restrict__ ssrc,
                                              u16* __restrict__ h,
                                              const float* __restrict__ Wl2,
                                              const float* __restrict__ Wr2,
                                              const float* __restrict__ bl2,
                                              float* __restrict__ z,
                                              float* __restrict__ r2) {
    __shared__ float2 sWl[128];
    __shared__ float2 sWr[128];
    const int tid = threadIdx.x;
    if (FUSE) {
        if (tid < 128) sWl[tid] = ((const float2*)Wl2)[tid];
        else sWr[tid - 128] = ((const float2*)Wr2)[tid - 128];
        __syncthreads();
    }
    const int lane = tid & 63;
    const int wv = tid >> 6;
    const int g = lane >> 4;
    const int i = lane & 15;
    const int node = blockIdx.x * 16 + wv * 4 + g;
    const int off0 = offsets[node];
    const int deg = offsets[node + 1] - off0;

    float acc[8] = {0.f, 0.f, 0.f, 0.f, 0.f, 0.f, 0.f, 0.f};

    int e = 0;
    for (; e + 3 < deg; e += 4) {
        int s0 = ssrc[off0 + e];
        int s1 = ssrc[off0 + e + 1];
        int s2 = ssrc[off0 + e + 2];
        int s3 = ssrc[off0 + e + 3];
        int4 v0 = *(const int4*)(yb + (size_t)s0 * 128 + i * 8);
        int4 v1 = *(const int4*)(yb + (size_t)s1 * 128 + i * 8);
        int4 v2 = *(const int4*)(yb + (size_t)s2 * 128 + i * 8);
        int4 v3 = *(const int4*)(yb + (size_t)s3 * 128 + i * 8);
        const unsigned* w0 = (const unsigned*)&v0;
        const unsigned* w1 = (const unsigned*)&v1;
        const unsigned* w2 = (const unsigned*)&v2;
        const unsigned* w3 = (const unsigned*)&v3;
#pragma unroll
        for (int q = 0; q < 4; ++q) {
            acc[q * 2]     += (bf_lo(w0[q]) + bf_lo(w1[q])) + (bf_lo(w2[q]) + bf_lo(w3[q]));
            acc[q * 2 + 1] += (bf_hi(w0[q]) + bf_hi(w1[q])) + (bf_hi(w2[q]) + bf_hi(w3[q]));
        }
    }
    for (; e < deg; ++e) {
        int s0 = ssrc[off0 + e];
        int4 v0 = *(const int4*)(yb + (size_t)s0 * 128 + i * 8);
        const unsigned* w0 = (const unsigned*)&v0;
#pragma unroll
        for (int q = 0; q < 4; ++q) {
            acc[q * 2]     += bf_lo(w0[q]);
            acc[q * 2 + 1] += bf_hi(w0[q]);
        }
    }

    float inv = 1.f / (float)max(deg, 1);
    int4 rv = *(const int4*)(rb + (size_t)node * 128 + i * 8);
    const unsigned* rw = (const unsigned*)&rv;
    float o[8];
#pragma unroll
    for (int q = 0; q < 4; ++q) {
        o[q * 2]     = fmaxf(acc[q * 2] * inv + bf_lo(rw[q]), 0.f);
        o[q * 2 + 1] = fmaxf(acc[q * 2 + 1] * inv + bf_hi(rw[q]), 0.f);
    }

    if (!FUSE) {
        int4 ov;
        ov.x = pk2(o[0], o[1]);
        ov.y = pk2(o[2], o[3]);
        ov.z = pk2(o[4], o[5]);
        ov.w = pk2(o[6], o[7]);
        *(int4*)(h + (size_t)node * 128 + i * 8) = ov;
    } else {
        float zl0 = 0.f, zl1 = 0.f, zr0 = 0.f, zr1 = 0.f;
#pragma unroll
        for (int j = 0; j < 8; ++j) {
            float2 wl = sWl[i * 8 + j];
            float2 wr = sWr[i * 8 + j];
            zl0 += o[j] * wl.x;
            zl1 += o[j] * wl.y;
            zr0 += o[j] * wr.x;
            zr1 += o[j] * wr.y;
        }
#pragma unroll
        for (int d = 1; d < 16; d <<= 1) {
            zl0 += __shfl_xor(zl0, d);
            zl1 += __shfl_xor(zl1, d);
            zr0 += __shfl_xor(zr0, d);
            zr1 += __shfl_xor(zr1, d);
        }
        if (i == 0) {
            float2 zv; zv.x = zl0; zv.y = zl1;
            float2 rv2; rv2.x = zr0 + bl2[0]; rv2.y = zr1 + bl2[1];
            *(float2*)(z + (size_t)node * 2) = zv;
            *(float2*)(r2 + (size_t)node * 2) = rv2;
        }
    }
}

// ---------------- layer 2 aggregation (2 channels) ----------------

__global__ __launch_bounds__(256) void k_agg2(const float* __restrict__ z,
                                              const float* __restrict__ r2,
                                              const int* __restrict__ offsets,
                                              const int* __restrict__ ssrc,
                                              float* __restrict__ out) {
    int n = blockIdx.x * 256 + threadIdx.x;
    if (n >= N_NODES) return;
    int off0 = offsets[n];
    int off1 = offsets[n + 1];
    float a0 = 0.f, a1 = 0.f;
    const float2* z2 = (const float2*)z;
    for (int e = off0; e < off1; ++e) {
        float2 v = z2[ssrc[e]];
        a0 += v.x;
        a1 += v.y;
    }
    float inv = 1.0f / (float)max(off1 - off0, 1);
    float2 rv = ((const float2*)r2)[n];
    float2 ov;
    ov.x = a0 * inv + rv.x;
    ov.y = a1 * inv + rv.y;
    ((float2*)out)[n] = ov;
}

// ---------------- launcher ----------------

extern "C" void kernel_launch(void* const* d_in, const int* in_sizes, int n_in,
                              void* d_out, int out_size, void* d_ws, size_t ws_size,
                              hipStream_t stream) {
    const float* x   = (const float*)d_in[0];
    const int*   ei  = (const int*)d_in[1];
    const float* Wl0 = (const float*)d_in[2];
    const float* bl0 = (const float*)d_in[3];
    const float* Wr0 = (const float*)d_in[4];
    const float* Wl1 = (const float*)d_in[5];
    const float* bl1 = (const float*)d_in[6];
    const float* Wr1 = (const float*)d_in[7];
    const float* Wl2 = (const float*)d_in[8];
    const float* bl2 = (const float*)d_in[9];
    const float* Wr2 = (const float*)d_in[10];
    float* out = (float*)d_out;

    const int* srcp = ei;
    const int* dstp = ei + N_EDGES;

    char* ws = (char*)d_ws;
    size_t off = 0;
    auto alloc = [&](size_t bytes) -> void* {
        void* p = ws + off;
        off += (bytes + 255) & ~(size_t)255;
        return p;
    };
    int* gcursor     = (int*)alloc(NBUCK * 4);        // offset 0 (pad to 1024)
    int* bucket_base = (int*)alloc((NBUCK + 1) * 4);
    int* offsets     = (int*)alloc((size_t)(N_NODES + 1) * 4);
    u32* stage       = (u32*)alloc((size_t)NBUCK * BCAP * 4);
    int* ssrc        = (int*)alloc((size_t)N_EDGES * 4);
    u16* wf0         = (u16*)alloc((size_t)192 * 256 * 2);
    u16* wf1         = (u16*)alloc((size_t)128 * 256 * 2);
    u16* ybuf        = (u16*)alloc((size_t)M_PAD * 128 * 2);
    u16* rbuf        = (u16*)alloc((size_t)M_PAD * 128 * 2);
    u16* h0          = (u16*)alloc((size_t)M_PAD * 128 * 2);
    float* zbuf      = (float*)alloc((size_t)N_NODES * 2 * 4);
    float* r2buf     = (float*)alloc((size_t)N_NODES * 2 * 4);
    (void)ws_size; (void)n_in; (void)in_sizes; (void)out_size;

    // ---- graph build ----
    hipMemsetAsync(gcursor, 0, 1024, stream);   // gcursor is atomically
    // accumulated every call -> must re-zero per launch (determinism).
    const int NB_SC = (N_EDGES / 4 + 1023) / 1024;   // 245
    k_scatter<<<NB_SC, 256, 0, stream>>>(srcp, dstp, gcursor, stage);
    k_bucketscan<<<1, 256, 0, stream>>>(gcursor, bucket_base, offsets);
    k_csr<<<NBUCK, 256, 0, stream>>>(stage, bucket_base, offsets, ssrc);

    // ---- weight conversion ----
    k_wprep<<<(192 / 32) * 16, 64, 0, stream>>>(Wl0, Wr0, IN_CH, wf0);
    k_wprep<<<(128 / 32) * 16, 64, 0, stream>>>(Wl1, Wr1, HID, wf1);

    // ---- layer 0 ----
    k_projmm0<<<NTILE, 512, 0, stream>>>(x, wf0, bl0, ybuf, rbuf);
    k_aggb<0><<<N_NODES / 16, 256, 0, stream>>>(ybuf, rbuf, offsets, ssrc,
                                                h0, nullptr, nullptr, nullptr,
                                                nullptr, nullptr);

    // ---- layer 1 (+ fused layer-2 projection) ----
    k_projmm1<<<NTILE, 512, 0, stream>>>(h0, wf1, bl1, ybuf, rbuf);
    k_aggb<1><<<N_NODES / 16, 256, 0, stream>>>(ybuf, rbuf, offsets, ssrc,
                                                nullptr, Wl2, Wr2, bl2,
                                                zbuf, r2buf);

    // ---- layer 2 aggregation ----
    k_agg2<<<(N_NODES + 255) / 256, 256, 0, stream>>>(zbuf, r2buf, offsets, ssrc, out);
}

// Round 14
// 160.186 us; speedup vs baseline: 3.3085x; 1.1772x over previous
//
#include <hip/hip_runtime.h>

#define N_NODES 100000
#define N_EDGES 1000000
#define IN_CH 166
#define HID 128
#define M_PAD 100032   // 1563 * 64
#define NTILE 1563
#define BSHIFT 9
#define NBUCK 196
#define BCAP 5632      // fixed bucket capacity (mean 5120, sd 72)

typedef unsigned char u8;
typedef unsigned short u16;
typedef unsigned int u32;
typedef __attribute__((ext_vector_type(8))) short short8;
typedef __attribute__((ext_vector_type(4))) float f32x4;
typedef __attribute__((ext_vector_type(2))) float f32x2;

static __device__ __forceinline__ u16 f2bf(float f) {
    unsigned u = __float_as_uint(f);
    u += 0x7FFF + ((u >> 16) & 1);   // RNE
    return (u16)(u >> 16);
}
static __device__ __forceinline__ unsigned pk2(float a, float b) {
    return (unsigned)f2bf(a) | ((unsigned)f2bf(b) << 16);
}
static __device__ __forceinline__ float bf_lo(unsigned w) {
    return __uint_as_float(w << 16);
}
static __device__ __forceinline__ float bf_hi(unsigned w) {
    return __uint_as_float(w & 0xFFFF0000u);
}

// ================= graph build =================

__global__ __launch_bounds__(256) void k_scatter(const int* __restrict__ src,
                                                 const int* __restrict__ dst,
                                                 int* __restrict__ gcursor,
                                                 u32* __restrict__ stage) {
    __shared__ int cnt[NBUCK];
    __shared__ int base[NBUCK];
    const int t = threadIdx.x;
    if (t < NBUCK) cnt[t] = 0;
    __syncthreads();

    int4 s4[4], d4[4];
    bool ok[4];
#pragma unroll
    for (int j = 0; j < 4; ++j) {
        int e4 = blockIdx.x * 1024 + j * 256 + t;
        ok[j] = (e4 < N_EDGES / 4);
        if (ok[j]) {
            s4[j] = ((const int4*)src)[e4];
            d4[j] = ((const int4*)dst)[e4];
            atomicAdd(&cnt[d4[j].x >> BSHIFT], 1);
            atomicAdd(&cnt[d4[j].y >> BSHIFT], 1);
            atomicAdd(&cnt[d4[j].z >> BSHIFT], 1);
            atomicAdd(&cnt[d4[j].w >> BSHIFT], 1);
        }
    }
    __syncthreads();
    if (t < NBUCK && cnt[t] > 0) base[t] = atomicAdd(&gcursor[t], cnt[t]);
    __syncthreads();

#pragma unroll
    for (int j = 0; j < 4; ++j) {
        if (ok[j]) {
            const int ss[4] = {s4[j].x, s4[j].y, s4[j].z, s4[j].w};
            const int dd[4] = {d4[j].x, d4[j].y, d4[j].z, d4[j].w};
#pragma unroll
            for (int q = 0; q < 4; ++q) {
                int b = dd[q] >> BSHIFT;
                int r = atomicSub(&cnt[b], 1) - 1;
                stage[(size_t)b * BCAP + base[b] + r] =
                    ((u32)ss[q] << 9) | (u32)(dd[q] & 511);
            }
        }
    }
}

__global__ __launch_bounds__(256) void k_bucketscan(const int* __restrict__ gcursor,
                                                    int* __restrict__ bucket_base,
                                                    int* __restrict__ offsets) {
    __shared__ int ws[256];
    const int t = threadIdx.x;
    int loc = (t < NBUCK) ? gcursor[t] : 0;
    ws[t] = loc;
    __syncthreads();
    int val = loc;
    for (int stp = 1; stp < 256; stp <<= 1) {
        int other = (t >= stp) ? ws[t - stp] : 0;
        __syncthreads();
        val += other;
        ws[t] = val;
        __syncthreads();
    }
    if (t < NBUCK) bucket_base[t] = val - loc;
    if (t == 255) bucket_base[NBUCK] = val;
    if (t == 0) offsets[N_NODES] = N_EDGES;
}

__global__ __launch_bounds__(256) void k_csr(const u32* __restrict__ stage,
                                             const int* __restrict__ bucket_base,
                                             int* __restrict__ offsets,
                                             int* __restrict__ ssrc) {
    __shared__ int cnt[512];
    __shared__ int ws[256];
    const int t = threadIdx.x;
    const int b = blockIdx.x;
    const int nb0 = b << BSHIFT;
    const int nn = min(512, N_NODES - nb0);
    const size_t e0s = (size_t)b * BCAP;
    const int e0 = bucket_base[b];
    const int m = bucket_base[b + 1] - e0;

    cnt[t] = 0;
    cnt[t + 256] = 0;
    __syncthreads();

    for (int i = t; i < m; i += 256) {
        u32 pr = stage[e0s + i];
        atomicAdd(&cnt[pr & 511], 1);
    }
    __syncthreads();

    int c0 = cnt[2 * t];
    int c1 = cnt[2 * t + 1];
    int loc = c0 + c1;
    ws[t] = loc;
    __syncthreads();
    int val = loc;
    for (int stp = 1; stp < 256; stp <<= 1) {
        int other = (t >= stp) ? ws[t - stp] : 0;
        __syncthreads();
        val += other;
        ws[t] = val;
        __syncthreads();
    }
    int p0 = e0 + (val - loc);
    int p1 = p0 + c0;
    if (2 * t < nn) offsets[nb0 + 2 * t] = p0;
    if (2 * t + 1 < nn) offsets[nb0 + 2 * t + 1] = p1;
    cnt[2 * t] = p0;
    cnt[2 * t + 1] = p1;
    __syncthreads();

    for (int i = t; i < m; i += 256) {
        u32 pr = stage[e0s + i];
        int p = atomicAdd(&cnt[pr & 511], 1);
        ssrc[p] = (int)(pr >> 9);
    }
}

// ---------------- weight prep: Wl|Wr -> bf16 MFMA fragments ----------------

__global__ __launch_bounds__(64) void k_wprep(const float* __restrict__ Wl,
                                              const float* __restrict__ Wr,
                                              int Kact, u16* __restrict__ wf) {
    int lane = threadIdx.x;
    int kt = blockIdx.x >> 4;
    int ct = blockIdx.x & 15;
    int col = ct * 16 + (lane & 15);
    const float* W = (col < 128) ? Wl : Wr;
    int wcol = col & 127;
    float v[8];
#pragma unroll
    for (int j = 0; j < 8; ++j) {
        int row = kt * 32 + (lane >> 4) * 8 + j;
        v[j] = (row < Kact) ? W[(size_t)row * 128 + wcol] : 0.f;
    }
    int4 o;
    o.x = pk2(v[0], v[1]);
    o.y = pk2(v[2], v[3]);
    o.z = pk2(v[4], v[5]);
    o.w = pk2(v[6], v[7]);
    *(int4*)(wf + ((size_t)blockIdx.x * 64 + lane) * 8) = o;
}

// ---------------- MFMA projection with LDS-transpose epilogue ------------
// y (gathered operand) is written as fp8 e4m3 (HW cvt); rb stays bf16.

#define STR2 136    // u16 stride for bf16 R phase
#define STRY 144    // byte stride for fp8 Y phase (16B multiple)

template <int KP>
static __device__ __forceinline__ void proj_tail(const u16* __restrict__ wf,
                                                 const float* __restrict__ bias,
                                                 u8* __restrict__ y,
                                                 u16* __restrict__ rb,
                                                 u16* sA, int n0) {
    constexpr int STR = KP + 8;
    const int tid = threadIdx.x;
    const int wv = tid >> 6;
    const int lane = tid & 63;
    const int rg = wv & 1;
    const int cg = wv >> 1;
    const int r16 = lane & 15;
    const int kq = lane >> 4;

    f32x4 acc[2][4];
#pragma unroll
    for (int a = 0; a < 2; ++a)
#pragma unroll
        for (int b = 0; b < 4; ++b) acc[a][b] = (f32x4){0.f, 0.f, 0.f, 0.f};

#pragma unroll
    for (int kt = 0; kt < KP / 32; ++kt) {
        short8 af[2], bf[4];
#pragma unroll
        for (int rt = 0; rt < 2; ++rt)
            af[rt] = *(const short8*)(&sA[(rg * 32 + rt * 16 + r16) * STR + kt * 32 + kq * 8]);
#pragma unroll
        for (int c = 0; c < 4; ++c)
            bf[c] = *(const short8*)(wf + (((size_t)(kt * 16 + cg * 4 + c) * 64 + lane) * 8));
#pragma unroll
        for (int rt = 0; rt < 2; ++rt)
#pragma unroll
            for (int c = 0; c < 4; ++c)
                acc[rt][c] = __builtin_amdgcn_mfma_f32_16x16x32_bf16(bf[c], af[rt], acc[rt][c], 0, 0, 0);
    }

    // ---- phase Y: cols 0..127 -> fp8 -> LDS -> coalesced int4 stores ----
    __syncthreads();   // staging dead
    u8* sB = (u8*)sA;
    if (cg < 2) {
#pragma unroll
        for (int rt = 0; rt < 2; ++rt) {
            int row = rg * 32 + rt * 16 + r16;
#pragma unroll
            for (int c = 0; c < 4; ++c) {
                int col = cg * 64 + c * 16 + kq * 4;
                int w = __builtin_amdgcn_cvt_pk_fp8_f32(acc[rt][c][0], acc[rt][c][1], 0, false);
                w = __builtin_amdgcn_cvt_pk_fp8_f32(acc[rt][c][2], acc[rt][c][3], w, true);
                *(int*)(&sB[row * STRY + col]) = w;
            }
        }
    }
    __syncthreads();
    {   // 64 rows x 128 B = 512 int4, one per thread
        int row = tid >> 3;
        int ch = tid & 7;
        int4 v = *(const int4*)(&sB[row * STRY + ch * 16]);
        *(int4*)(y + (size_t)(n0 + row) * 128 + ch * 16) = v;
    }
    // ---- phase R: cols 128..255 (+bias), bf16 ----
    __syncthreads();
    if (cg >= 2) {
#pragma unroll
        for (int rt = 0; rt < 2; ++rt) {
            int row = rg * 32 + rt * 16 + r16;
#pragma unroll
            for (int c = 0; c < 4; ++c) {
                int col = (cg - 2) * 64 + c * 16 + kq * 4;
                float4 bv = *(const float4*)&bias[col];
                int2 ov;
                ov.x = pk2(acc[rt][c][0] + bv.x, acc[rt][c][1] + bv.y);
                ov.y = pk2(acc[rt][c][2] + bv.z, acc[rt][c][3] + bv.w);
                *(int2*)(&sA[row * STR2 + col]) = ov;
            }
        }
    }
    __syncthreads();
#pragma unroll
    for (int p = 0; p < 2; ++p) {
        int c = p * 512 + tid;
        int row = c >> 4;
        int ch = c & 15;
        int4 v = *(const int4*)(&sA[row * STR2 + ch * 8]);
        *(int4*)(rb + (size_t)(n0 + row) * 128 + ch * 8) = v;
    }
}

// layer 0: fp32 x [N,166]; tile = exactly 2656 aligned float4
__global__ __launch_bounds__(512, 4) void k_projmm0(const float* __restrict__ in,
                                                    const u16* __restrict__ wf,
                                                    const float* __restrict__ bias,
                                                    u8* __restrict__ y,
                                                    u16* __restrict__ rb) {
    constexpr int KP = 192;
    constexpr int STR = KP + 8;   // 200
    __shared__ u16 sA[64 * STR];
    const int tid = threadIdx.x;
    const int n0 = blockIdx.x * 64;

    // zero-fill K pad cols 166..191 (u32 writes: 13 per row)
    for (int c = tid; c < 64 * 13; c += 512) {
        int row = c / 13;
        int col = 166 + (c - row * 13) * 2;
        *(unsigned*)(&sA[row * STR + col]) = 0;
    }
    // zero-fill padding node rows of the last tile
    if (n0 + 63 >= N_NODES) {
        for (int c = tid; c < 64 * 83; c += 512) {
            int row = c / 83;
            if (n0 + row >= N_NODES)
                *(unsigned*)(&sA[row * STR + (c - row * 83) * 2]) = 0;
        }
    }
    // flat float4 staging: element e = f*4+j -> (row=e/166, k=e%166)
    const float4* x4 = (const float4*)in;
    const size_t gbase = (size_t)blockIdx.x * 2656;
#pragma unroll
    for (int it = 0; it < 6; ++it) {
        int f = it * 512 + tid;
        size_t gf = gbase + f;
        if (f < 2656 && gf < (size_t)N_NODES * IN_CH / 4) {
            float4 v = x4[gf];
            int e0 = f * 4;
            int row = e0 / IN_CH;
            int k = e0 - row * IN_CH;
            if (k <= IN_CH - 4) {   // fast path (97.6%)
                *(unsigned*)(&sA[row * STR + k]) = pk2(v.x, v.y);
                *(unsigned*)(&sA[row * STR + k + 2]) = pk2(v.z, v.w);
            } else {
                const float vv[4] = {v.x, v.y, v.z, v.w};
#pragma unroll
                for (int j = 0; j < 4; ++j) {
                    int kk = k + j;
                    int r = row, c = kk;
                    if (kk >= IN_CH) { r = row + 1; c = kk - IN_CH; }
                    sA[r * STR + c] = f2bf(vv[j]);
                }
            }
        }
    }
    __syncthreads();
    proj_tail<KP>(wf, bias, y, rb, sA, n0);
}

// layer 1: bf16 input [M_PAD,128]
__global__ __launch_bounds__(512, 4) void k_projmm1(const u16* __restrict__ in,
                                                    const u16* __restrict__ wf,
                                                    const float* __restrict__ bias,
                                                    u8* __restrict__ y,
                                                    u16* __restrict__ rb) {
    constexpr int KP = 128;
    constexpr int STR = KP + 8;
    __shared__ u16 sA[64 * STR];
    const int tid = threadIdx.x;
    const int n0 = blockIdx.x * 64;

#pragma unroll
    for (int it = 0; it < 2; ++it) {
        int c = it * 512 + tid;
        int row = c >> 4;
        int cc = c & 15;
        int4 v = *(const int4*)(in + (size_t)(n0 + row) * KP + cc * 8);
        *(int4*)(&sA[row * STR + cc * 8]) = v;
    }
    __syncthreads();
    proj_tail<KP>(wf, bias, y, rb, sA, n0);
}

// ---------------- aggregation (fp8 gather; optional fused layer-2) ---

static __device__ __forceinline__ void acc_fp8(float* acc, int2 v) {
    f32x2 p;
    p = __builtin_amdgcn_cvt_pk_f32_fp8(v.x, false); acc[0] += p.x; acc[1] += p.y;
    p = __builtin_amdgcn_cvt_pk_f32_fp8(v.x, true);  acc[2] += p.x; acc[3] += p.y;
    p = __builtin_amdgcn_cvt_pk_f32_fp8(v.y, false); acc[4] += p.x; acc[5] += p.y;
    p = __builtin_amdgcn_cvt_pk_f32_fp8(v.y, true);  acc[6] += p.x; acc[7] += p.y;
}

template <int FUSE>
__global__ __launch_bounds__(256) void k_aggb(const u8* __restrict__ yb,
                                              const u16* __restrict__ rb,
                                              const int* __restrict__ offsets,
                                              const int* __restrict__ ssrc,
                                              u16* __restrict__ h,
                                              const float* __restrict__ Wl2,
                                              const float* __restrict__ Wr2,
                                              const float* __restrict__ bl2,
                                              float* __restrict__ z,
                                              float* __restrict__ r2) {
    __shared__ float2 sWl[128];
    __shared__ float2 sWr[128];
    const int tid = threadIdx.x;
    if (FUSE) {
        if (tid < 128) sWl[tid] = ((const float2*)Wl2)[tid];
        else sWr[tid - 128] = ((const float2*)Wr2)[tid - 128];
        __syncthreads();
    }
    const int lane = tid & 63;
    const int wv = tid >> 6;
    const int g = lane >> 4;
    const int i = lane & 15;
    const int node = blockIdx.x * 16 + wv * 4 + g;
    const int off0 = offsets[node];
    const int deg = offsets[node + 1] - off0;

    float acc[8] = {0.f, 0.f, 0.f, 0.f, 0.f, 0.f, 0.f, 0.f};

    int e = 0;
    for (; e + 3 < deg; e += 4) {
        int s0 = ssrc[off0 + e];
        int s1 = ssrc[off0 + e + 1];
        int s2 = ssrc[off0 + e + 2];
        int s3 = ssrc[off0 + e + 3];
        int2 v0 = *(const int2*)(yb + (size_t)s0 * 128 + i * 8);
        int2 v1 = *(const int2*)(yb + (size_t)s1 * 128 + i * 8);
        int2 v2 = *(const int2*)(yb + (size_t)s2 * 128 + i * 8);
        int2 v3 = *(const int2*)(yb + (size_t)s3 * 128 + i * 8);
        acc_fp8(acc, v0);
        acc_fp8(acc, v1);
        acc_fp8(acc, v2);
        acc_fp8(acc, v3);
    }
    for (; e < deg; ++e) {
        int s0 = ssrc[off0 + e];
        int2 v0 = *(const int2*)(yb + (size_t)s0 * 128 + i * 8);
        acc_fp8(acc, v0);
    }

    float inv = 1.f / (float)max(deg, 1);
    int4 rv = *(const int4*)(rb + (size_t)node * 128 + i * 8);
    const unsigned* rw = (const unsigned*)&rv;
    float o[8];
#pragma unroll
    for (int q = 0; q < 4; ++q) {
        o[q * 2]     = fmaxf(acc[q * 2] * inv + bf_lo(rw[q]), 0.f);
        o[q * 2 + 1] = fmaxf(acc[q * 2 + 1] * inv + bf_hi(rw[q]), 0.f);
    }

    if (!FUSE) {
        int4 ov;
        ov.x = pk2(o[0], o[1]);
        ov.y = pk2(o[2], o[3]);
        ov.z = pk2(o[4], o[5]);
        ov.w = pk2(o[6], o[7]);
        *(int4*)(h + (size_t)node * 128 + i * 8) = ov;
    } else {
        float zl0 = 0.f, zl1 = 0.f, zr0 = 0.f, zr1 = 0.f;
#pragma unroll
        for (int j = 0; j < 8; ++j) {
            float2 wl = sWl[i * 8 + j];
            float2 wr = sWr[i * 8 + j];
            zl0 += o[j] * wl.x;
            zl1 += o[j] * wl.y;
            zr0 += o[j] * wr.x;
            zr1 += o[j] * wr.y;
        }
#pragma unroll
        for (int d = 1; d < 16; d <<= 1) {
            zl0 += __shfl_xor(zl0, d);
            zl1 += __shfl_xor(zl1, d);
            zr0 += __shfl_xor(zr0, d);
            zr1 += __shfl_xor(zr1, d);
        }
        if (i == 0) {
            float2 zv; zv.x = zl0; zv.y = zl1;
            float2 rv2; rv2.x = zr0 + bl2[0]; rv2.y = zr1 + bl2[1];
            *(float2*)(z + (size_t)node * 2) = zv;
            *(float2*)(r2 + (size_t)node * 2) = rv2;
        }
    }
}

// ---------------- layer 2 aggregation (2 channels) ----------------

__global__ __launch_bounds__(256) void k_agg2(const float* __restrict__ z,
                                              const float* __restrict__ r2,
                                              const int* __restrict__ offsets,
                                              const int* __restrict__ ssrc,
                                              float* __restrict__ out) {
    int n = blockIdx.x * 256 + threadIdx.x;
    if (n >= N_NODES) return;
    int off0 = offsets[n];
    int off1 = offsets[n + 1];
    float a0 = 0.f, a1 = 0.f;
    const float2* z2 = (const float2*)z;
    for (int e = off0; e < off1; ++e) {
        float2 v = z2[ssrc[e]];
        a0 += v.x;
        a1 += v.y;
    }
    float inv = 1.0f / (float)max(off1 - off0, 1);
    float2 rv = ((const float2*)r2)[n];
    float2 ov;
    ov.x = a0 * inv + rv.x;
    ov.y = a1 * inv + rv.y;
    ((float2*)out)[n] = ov;
}

// ---------------- launcher ----------------

extern "C" void kernel_launch(void* const* d_in, const int* in_sizes, int n_in,
                              void* d_out, int out_size, void* d_ws, size_t ws_size,
                              hipStream_t stream) {
    const float* x   = (const float*)d_in[0];
    const int*   ei  = (const int*)d_in[1];
    const float* Wl0 = (const float*)d_in[2];
    const float* bl0 = (const float*)d_in[3];
    const float* Wr0 = (const float*)d_in[4];
    const float* Wl1 = (const float*)d_in[5];
    const float* bl1 = (const float*)d_in[6];
    const float* Wr1 = (const float*)d_in[7];
    const float* Wl2 = (const float*)d_in[8];
    const float* bl2 = (const float*)d_in[9];
    const float* Wr2 = (const float*)d_in[10];
    float* out = (float*)d_out;

    const int* srcp = ei;
    const int* dstp = ei + N_EDGES;

    char* ws = (char*)d_ws;
    size_t off = 0;
    auto alloc = [&](size_t bytes) -> void* {
        void* p = ws + off;
        off += (bytes + 255) & ~(size_t)255;
        return p;
    };
    int* gcursor     = (int*)alloc(NBUCK * 4);
    int* bucket_base = (int*)alloc((NBUCK + 1) * 4);
    int* offsets     = (int*)alloc((size_t)(N_NODES + 1) * 4);
    u32* stage       = (u32*)alloc((size_t)NBUCK * BCAP * 4);
    int* ssrc        = (int*)alloc((size_t)N_EDGES * 4);
    u16* wf0         = (u16*)alloc((size_t)192 * 256 * 2);
    u16* wf1         = (u16*)alloc((size_t)128 * 256 * 2);
    u8* ybuf         = (u8*)alloc((size_t)M_PAD * 128);
    u16* rbuf        = (u16*)alloc((size_t)M_PAD * 128 * 2);
    u16* h0          = (u16*)alloc((size_t)M_PAD * 128 * 2);
    float* zbuf      = (float*)alloc((size_t)N_NODES * 2 * 4);
    float* r2buf     = (float*)alloc((size_t)N_NODES * 2 * 4);
    (void)ws_size; (void)n_in; (void)in_sizes; (void)out_size;

    // ---- graph build ----
    hipMemsetAsync(gcursor, 0, 1024, stream);   // gcursor re-zeroed per launch
    const int NB_SC = (N_EDGES / 4 + 1023) / 1024;   // 245
    k_scatter<<<NB_SC, 256, 0, stream>>>(srcp, dstp, gcursor, stage);
    k_bucketscan<<<1, 256, 0, stream>>>(gcursor, bucket_base, offsets);
    k_csr<<<NBUCK, 256, 0, stream>>>(stage, bucket_base, offsets, ssrc);

    // ---- weight conversion ----
    k_wprep<<<(192 / 32) * 16, 64, 0, stream>>>(Wl0, Wr0, IN_CH, wf0);
    k_wprep<<<(128 / 32) * 16, 64, 0, stream>>>(Wl1, Wr1, HID, wf1);

    // ---- layer 0 ----
    k_projmm0<<<NTILE, 512, 0, stream>>>(x, wf0, bl0, ybuf, rbuf);
    k_aggb<0><<<N_NODES / 16, 256, 0, stream>>>(ybuf, rbuf, offsets, ssrc,
                                                h0, nullptr, nullptr, nullptr,
                                                nullptr, nullptr);

    // ---- layer 1 (+ fused layer-2 projection) ----
    k_projmm1<<<NTILE, 512, 0, stream>>>(h0, wf1, bl1, ybuf, rbuf);
    k_aggb<1><<<N_NODES / 16, 256, 0, stream>>>(ybuf, rbuf, offsets, ssrc,
                                                nullptr, Wl2, Wr2, bl2,
                                                zbuf, r2buf);

    // ---- layer 2 aggregation ----
    k_agg2<<<(N_NODES + 255) / 256, 256, 0, stream>>>(zbuf, r2buf, offsets, ssrc, out);
}

// Round 16
// 159.785 us; speedup vs baseline: 3.3168x; 1.0025x over previous
//
#include <hip/hip_runtime.h>

#define N_NODES 100000
#define N_EDGES 1000000
#define IN_CH 166
#define HID 128
#define NTILE32 3125   // 100000 / 32 exactly
#define BSHIFT 9
#define NBUCK 196
#define BCAP 5632      // fixed bucket capacity (mean 5120, sd 72)

typedef unsigned char u8;
typedef unsigned short u16;
typedef unsigned int u32;
typedef __attribute__((ext_vector_type(8))) short short8;
typedef __attribute__((ext_vector_type(4))) float f32x4;
typedef __attribute__((ext_vector_type(2))) float f32x2;

static __device__ __forceinline__ u16 f2bf(float f) {
    unsigned u = __float_as_uint(f);
    u += 0x7FFF + ((u >> 16) & 1);   // RNE
    return (u16)(u >> 16);
}
static __device__ __forceinline__ unsigned pk2(float a, float b) {
    return (unsigned)f2bf(a) | ((unsigned)f2bf(b) << 16);
}
static __device__ __forceinline__ float bf_lo(unsigned w) {
    return __uint_as_float(w << 16);
}
static __device__ __forceinline__ float bf_hi(unsigned w) {
    return __uint_as_float(w & 0xFFFF0000u);
}

// ================= graph build =================

__global__ void k_zero(int* __restrict__ p) {
    p[threadIdx.x] = 0;   // 256 >= NBUCK
}

__global__ __launch_bounds__(256) void k_scatter(const int* __restrict__ src,
                                                 const int* __restrict__ dst,
                                                 int* __restrict__ gcursor,
                                                 u32* __restrict__ stage) {
    __shared__ int cnt[NBUCK];
    __shared__ int base[NBUCK];
    const int t = threadIdx.x;
    if (t < NBUCK) cnt[t] = 0;
    __syncthreads();

    int4 s4[4], d4[4];
    bool ok[4];
#pragma unroll
    for (int j = 0; j < 4; ++j) {
        int e4 = blockIdx.x * 1024 + j * 256 + t;
        ok[j] = (e4 < N_EDGES / 4);
        if (ok[j]) {
            s4[j] = ((const int4*)src)[e4];
            d4[j] = ((const int4*)dst)[e4];
            atomicAdd(&cnt[d4[j].x >> BSHIFT], 1);
            atomicAdd(&cnt[d4[j].y >> BSHIFT], 1);
            atomicAdd(&cnt[d4[j].z >> BSHIFT], 1);
            atomicAdd(&cnt[d4[j].w >> BSHIFT], 1);
        }
    }
    __syncthreads();
    if (t < NBUCK && cnt[t] > 0) base[t] = atomicAdd(&gcursor[t], cnt[t]);
    __syncthreads();

#pragma unroll
    for (int j = 0; j < 4; ++j) {
        if (ok[j]) {
            const int ss[4] = {s4[j].x, s4[j].y, s4[j].z, s4[j].w};
            const int dd[4] = {d4[j].x, d4[j].y, d4[j].z, d4[j].w};
#pragma unroll
            for (int q = 0; q < 4; ++q) {
                int b = dd[q] >> BSHIFT;
                int r = atomicSub(&cnt[b], 1) - 1;
                stage[(size_t)b * BCAP + base[b] + r] =
                    ((u32)ss[q] << 9) | (u32)(dd[q] & 511);
            }
        }
    }
}

__global__ __launch_bounds__(256) void k_bucketscan(const int* __restrict__ gcursor,
                                                    int* __restrict__ bucket_base,
                                                    int* __restrict__ offsets) {
    __shared__ int ws[256];
    const int t = threadIdx.x;
    int loc = (t < NBUCK) ? gcursor[t] : 0;
    ws[t] = loc;
    __syncthreads();
    int val = loc;
    for (int stp = 1; stp < 256; stp <<= 1) {
        int other = (t >= stp) ? ws[t - stp] : 0;
        __syncthreads();
        val += other;
        ws[t] = val;
        __syncthreads();
    }
    if (t < NBUCK) bucket_base[t] = val - loc;
    if (t == 255) bucket_base[NBUCK] = val;
    if (t == 0) offsets[N_NODES] = N_EDGES;
}

__global__ __launch_bounds__(256) void k_csr(const u32* __restrict__ stage,
                                             const int* __restrict__ bucket_base,
                                             int* __restrict__ offsets,
                                             int* __restrict__ ssrc) {
    __shared__ int cnt[512];
    __shared__ int ws[256];
    const int t = threadIdx.x;
    const int b = blockIdx.x;
    const int nb0 = b << BSHIFT;
    const int nn = min(512, N_NODES - nb0);
    const size_t e0s = (size_t)b * BCAP;
    const int e0 = bucket_base[b];
    const int m = bucket_base[b + 1] - e0;

    cnt[t] = 0;
    cnt[t + 256] = 0;
    __syncthreads();

    for (int i = t; i < m; i += 256) {
        u32 pr = stage[e0s + i];
        atomicAdd(&cnt[pr & 511], 1);
    }
    __syncthreads();

    int c0 = cnt[2 * t];
    int c1 = cnt[2 * t + 1];
    int loc = c0 + c1;
    ws[t] = loc;
    __syncthreads();
    int val = loc;
    for (int stp = 1; stp < 256; stp <<= 1) {
        int other = (t >= stp) ? ws[t - stp] : 0;
        __syncthreads();
        val += other;
        ws[t] = val;
        __syncthreads();
    }
    int p0 = e0 + (val - loc);
    int p1 = p0 + c0;
    if (2 * t < nn) offsets[nb0 + 2 * t] = p0;
    if (2 * t + 1 < nn) offsets[nb0 + 2 * t + 1] = p1;
    cnt[2 * t] = p0;
    cnt[2 * t + 1] = p1;
    __syncthreads();

    for (int i = t; i < m; i += 256) {
        u32 pr = stage[e0s + i];
        int p = atomicAdd(&cnt[pr & 511], 1);
        ssrc[p] = (int)(pr >> 9);
    }
}

// ---------------- weight prep: Wl|Wr -> bf16 MFMA fragments ----------------

__global__ __launch_bounds__(64) void k_wprep(const float* __restrict__ Wl,
                                              const float* __restrict__ Wr,
                                              int Kact, u16* __restrict__ wf) {
    int lane = threadIdx.x;
    int kt = blockIdx.x >> 4;
    int ct = blockIdx.x & 15;
    int col = ct * 16 + (lane & 15);
    const float* W = (col < 128) ? Wl : Wr;
    int wcol = col & 127;
    float v[8];
#pragma unroll
    for (int j = 0; j < 8; ++j) {
        int row = kt * 32 + (lane >> 4) * 8 + j;
        v[j] = (row < Kact) ? W[(size_t)row * 128 + wcol] : 0.f;
    }
    int4 o;
    o.x = pk2(v[0], v[1]);
    o.y = pk2(v[2], v[3]);
    o.z = pk2(v[4], v[5]);
    o.w = pk2(v[6], v[7]);
    *(int4*)(wf + ((size_t)blockIdx.x * 64 + lane) * 8) = o;
}

// ---------------- MFMA projection, 32-row tiles, 256 threads -------------
// 4 waves; wave wv = col-group cg (0..3): cols cg*64..+63, all 32 rows.
// swapped operands: lane&15 = node row, (lane>>4)*4+i = output col.
// y written fp8 e4m3 (HW cvt); rb bf16. LDS-transpose epilogue.

#define STR2 136    // u16 stride for bf16 R phase
#define STRY 144    // byte stride for fp8 Y phase

template <int KP>
static __device__ __forceinline__ void proj_tail(const u16* __restrict__ wf,
                                                 const float* __restrict__ bias,
                                                 u8* __restrict__ y,
                                                 u16* __restrict__ rb,
                                                 u16* sA, int n0) {
    constexpr int STR = KP + 8;
    const int tid = threadIdx.x;
    const int cg = tid >> 6;      // 0..3
    const int lane = tid & 63;
    const int r16 = lane & 15;
    const int kq = lane >> 4;

    f32x4 acc[2][4];
#pragma unroll
    for (int a = 0; a < 2; ++a)
#pragma unroll
        for (int b = 0; b < 4; ++b) acc[a][b] = (f32x4){0.f, 0.f, 0.f, 0.f};

#pragma unroll
    for (int kt = 0; kt < KP / 32; ++kt) {
        short8 af[2], bf[4];
#pragma unroll
        for (int rt = 0; rt < 2; ++rt)
            af[rt] = *(const short8*)(&sA[(rt * 16 + r16) * STR + kt * 32 + kq * 8]);
#pragma unroll
        for (int c = 0; c < 4; ++c)
            bf[c] = *(const short8*)(wf + (((size_t)(kt * 16 + cg * 4 + c) * 64 + lane) * 8));
#pragma unroll
        for (int rt = 0; rt < 2; ++rt)
#pragma unroll
            for (int c = 0; c < 4; ++c)
                acc[rt][c] = __builtin_amdgcn_mfma_f32_16x16x32_bf16(bf[c], af[rt], acc[rt][c], 0, 0, 0);
    }

    // ---- phase Y: cols 0..127 -> fp8 -> LDS -> coalesced int4 stores ----
    __syncthreads();   // staging dead
    u8* sB = (u8*)sA;
    if (cg < 2) {
#pragma unroll
        for (int rt = 0; rt < 2; ++rt) {
            int row = rt * 16 + r16;
#pragma unroll
            for (int c = 0; c < 4; ++c) {
                int col = cg * 64 + c * 16 + kq * 4;
                int w = __builtin_amdgcn_cvt_pk_fp8_f32(acc[rt][c][0], acc[rt][c][1], 0, false);
                w = __builtin_amdgcn_cvt_pk_fp8_f32(acc[rt][c][2], acc[rt][c][3], w, true);
                *(int*)(&sB[row * STRY + col]) = w;
            }
        }
    }
    __syncthreads();
    {   // 32 rows x 8 int4 = 256, one per thread
        int row = tid >> 3;
        int ch = tid & 7;
        int4 v = *(const int4*)(&sB[row * STRY + ch * 16]);
        *(int4*)(y + (size_t)(n0 + row) * 128 + ch * 16) = v;
    }
    // ---- phase R: cols 128..255 (+bias), bf16 ----
    __syncthreads();
    if (cg >= 2) {
#pragma unroll
        for (int rt = 0; rt < 2; ++rt) {
            int row = rt * 16 + r16;
#pragma unroll
            for (int c = 0; c < 4; ++c) {
                int col = (cg - 2) * 64 + c * 16 + kq * 4;
                float4 bv = *(const float4*)&bias[col];
                int2 ov;
                ov.x = pk2(acc[rt][c][0] + bv.x, acc[rt][c][1] + bv.y);
                ov.y = pk2(acc[rt][c][2] + bv.z, acc[rt][c][3] + bv.w);
                *(int2*)(&sA[row * STR2 + col]) = ov;
            }
        }
    }
    __syncthreads();
#pragma unroll
    for (int p = 0; p < 2; ++p) {
        int c = p * 256 + tid;   // 32 rows x 16 int4 = 512
        int row = c >> 4;
        int ch = c & 15;
        int4 v = *(const int4*)(&sA[row * STR2 + ch * 8]);
        *(int4*)(rb + (size_t)(n0 + row) * 128 + ch * 8) = v;
    }
}

// layer 0: fp32 x [N,166]; 32-row tile = exactly 1328 aligned float4
__global__ __launch_bounds__(256, 8) void k_projmm0(const float* __restrict__ in,
                                                    const u16* __restrict__ wf,
                                                    const float* __restrict__ bias,
                                                    u8* __restrict__ y,
                                                    u16* __restrict__ rb) {
    constexpr int KP = 192;
    constexpr int STR = KP + 8;   // 200
    __shared__ u16 sA[32 * STR];  // 12.8 KB
    const int tid = threadIdx.x;
    const int n0 = blockIdx.x * 32;

    // zero-fill K pad cols 166..191: 32 rows x 13 u32 = 416 writes (strided!)
    for (int c = tid; c < 32 * 13; c += 256) {
        int row = c / 13;
        int col = 166 + (c - row * 13) * 2;
        *(unsigned*)(&sA[row * STR + col]) = 0;
    }
    // flat float4 staging: element e = f*4+j -> (row=e/166, k=e%166)
    const float4* x4 = (const float4*)in;
    const size_t gbase = (size_t)blockIdx.x * 1328;
#pragma unroll
    for (int it = 0; it < 6; ++it) {
        int f = it * 256 + tid;
        if (f < 1328) {
            float4 v = x4[gbase + f];
            int e0 = f * 4;
            int row = e0 / IN_CH;
            int k = e0 - row * IN_CH;
            if (k <= IN_CH - 4) {   // fast path (97.6%)
                *(unsigned*)(&sA[row * STR + k]) = pk2(v.x, v.y);
                *(unsigned*)(&sA[row * STR + k + 2]) = pk2(v.z, v.w);
            } else {
                const float vv[4] = {v.x, v.y, v.z, v.w};
#pragma unroll
                for (int j = 0; j < 4; ++j) {
                    int kk = k + j;
                    int r = row, c = kk;
                    if (kk >= IN_CH) { r = row + 1; c = kk - IN_CH; }
                    if (r < 32) sA[r * STR + c] = f2bf(vv[j]);
                }
            }
        }
    }
    __syncthreads();
    proj_tail<KP>(wf, bias, y, rb, sA, n0);
}

// layer 1: bf16 input [N,128], 32-row tile
__global__ __launch_bounds__(256, 8) void k_projmm1(const u16* __restrict__ in,
                                                    const u16* __restrict__ wf,
                                                    const float* __restrict__ bias,
                                                    u8* __restrict__ y,
                                                    u16* __restrict__ rb) {
    constexpr int KP = 128;
    constexpr int STR = KP + 8;   // 136
    __shared__ u16 sA[32 * STR];  // 8.7 KB
    const int tid = threadIdx.x;
    const int n0 = blockIdx.x * 32;

#pragma unroll
    for (int it = 0; it < 2; ++it) {
        int c = it * 256 + tid;   // 32 rows x 16 int4
        int row = c >> 4;
        int cc = c & 15;
        int4 v = *(const int4*)(in + (size_t)(n0 + row) * KP + cc * 8);
        *(int4*)(&sA[row * STR + cc * 8]) = v;
    }
    __syncthreads();
    proj_tail<KP>(wf, bias, y, rb, sA, n0);
}

// ---------------- aggregation (fp8 gather; optional fused layer-2) ---

static __device__ __forceinline__ void acc_fp8(float* acc, int2 v) {
    f32x2 p;
    p = __builtin_amdgcn_cvt_pk_f32_fp8(v.x, false); acc[0] += p.x; acc[1] += p.y;
    p = __builtin_amdgcn_cvt_pk_f32_fp8(v.x, true);  acc[2] += p.x; acc[3] += p.y;
    p = __builtin_amdgcn_cvt_pk_f32_fp8(v.y, false); acc[4] += p.x; acc[5] += p.y;
    p = __builtin_amdgcn_cvt_pk_f32_fp8(v.y, true);  acc[6] += p.x; acc[7] += p.y;
}

template <int FUSE>
__global__ __launch_bounds__(256) void k_aggb(const u8* __restrict__ yb,
                                              const u16* __restrict__ rb,
                                              const int* __restrict__ offsets,
                                              const int* __restrict__ ssrc,
                                              u16* __restrict__ h,
                                              const float* __restrict__ Wl2,
                                              const float* __restrict__ Wr2,
                                              const float* __restrict__ bl2,
                                              float* __restrict__ z,
                                              float* __restrict__ r2) {
    __shared__ float2 sWl[128];
    __shared__ float2 sWr[128];
    const int tid = threadIdx.x;
    if (FUSE) {
        if (tid < 128) sWl[tid] = ((const float2*)Wl2)[tid];
        else sWr[tid - 128] = ((const float2*)Wr2)[tid - 128];
        __syncthreads();
    }
    const int lane = tid & 63;
    const int wv = tid >> 6;
    const int g = lane >> 4;
    const int i = lane & 15;
    const int node = blockIdx.x * 16 + wv * 4 + g;
    const int off0 = offsets[node];
    const int deg = offsets[node + 1] - off0;

    float acc[8] = {0.f, 0.f, 0.f, 0.f, 0.f, 0.f, 0.f, 0.f};

    int e = 0;
    for (; e + 3 < deg; e += 4) {
        int s0 = ssrc[off0 + e];
        int s1 = ssrc[off0 + e + 1];
        int s2 = ssrc[off0 + e + 2];
        int s3 = ssrc[off0 + e + 3];
        int2 v0 = *(const int2*)(yb + (size_t)s0 * 128 + i * 8);
        int2 v1 = *(const int2*)(yb + (size_t)s1 * 128 + i * 8);
        int2 v2 = *(const int2*)(yb + (size_t)s2 * 128 + i * 8);
        int2 v3 = *(const int2*)(yb + (size_t)s3 * 128 + i * 8);
        acc_fp8(acc, v0);
        acc_fp8(acc, v1);
        acc_fp8(acc, v2);
        acc_fp8(acc, v3);
    }
    for (; e < deg; ++e) {
        int s0 = ssrc[off0 + e];
        int2 v0 = *(const int2*)(yb + (size_t)s0 * 128 + i * 8);
        acc_fp8(acc, v0);
    }

    float inv = 1.f / (float)max(deg, 1);
    int4 rv = *(const int4*)(rb + (size_t)node * 128 + i * 8);
    const unsigned* rw = (const unsigned*)&rv;
    float o[8];
#pragma unroll
    for (int q = 0; q < 4; ++q) {
        o[q * 2]     = fmaxf(acc[q * 2] * inv + bf_lo(rw[q]), 0.f);
        o[q * 2 + 1] = fmaxf(acc[q * 2 + 1] * inv + bf_hi(rw[q]), 0.f);
    }

    if (!FUSE) {
        int4 ov;
        ov.x = pk2(o[0], o[1]);
        ov.y = pk2(o[2], o[3]);
        ov.z = pk2(o[4], o[5]);
        ov.w = pk2(o[6], o[7]);
        *(int4*)(h + (size_t)node * 128 + i * 8) = ov;
    } else {
        float zl0 = 0.f, zl1 = 0.f, zr0 = 0.f, zr1 = 0.f;
#pragma unroll
        for (int j = 0; j < 8; ++j) {
            float2 wl = sWl[i * 8 + j];
            float2 wr = sWr[i * 8 + j];
            zl0 += o[j] * wl.x;
            zl1 += o[j] * wl.y;
            zr0 += o[j] * wr.x;
            zr1 += o[j] * wr.y;
        }
#pragma unroll
        for (int d = 1; d < 16; d <<= 1) {
            zl0 += __shfl_xor(zl0, d);
            zl1 += __shfl_xor(zl1, d);
            zr0 += __shfl_xor(zr0, d);
            zr1 += __shfl_xor(zr1, d);
        }
        if (i == 0) {
            float2 zv; zv.x = zl0; zv.y = zl1;
            float2 rv2; rv2.x = zr0 + bl2[0]; rv2.y = zr1 + bl2[1];
            *(float2*)(z + (size_t)node * 2) = zv;
            *(float2*)(r2 + (size_t)node * 2) = rv2;
        }
    }
}

// ---------------- layer 2 aggregation (2 channels) ----------------

__global__ __launch_bounds__(256) void k_agg2(const float* __restrict__ z,
                                              const float* __restrict__ r2,
                                              const int* __restrict__ offsets,
                                              const int* __restrict__ ssrc,
                                              float* __restrict__ out) {
    int n = blockIdx.x * 256 + threadIdx.x;
    if (n >= N_NODES) return;
    int off0 = offsets[n];
    int off1 = offsets[n + 1];
    float a0 = 0.f, a1 = 0.f;
    const float2* z2 = (const float2*)z;
    for (int e = off0; e < off1; ++e) {
        float2 v = z2[ssrc[e]];
        a0 += v.x;
        a1 += v.y;
    }
    float inv = 1.0f / (float)max(off1 - off0, 1);
    float2 rv = ((const float2*)r2)[n];
    float2 ov;
    ov.x = a0 * inv + rv.x;
    ov.y = a1 * inv + rv.y;
    ((float2*)out)[n] = ov;
}

// ---------------- launcher ----------------

extern "C" void kernel_launch(void* const* d_in, const int* in_sizes, int n_in,
                              void* d_out, int out_size, void* d_ws, size_t ws_size,
                              hipStream_t stream) {
    const float* x   = (const float*)d_in[0];
    const int*   ei  = (const int*)d_in[1];
    const float* Wl0 = (const float*)d_in[2];
    const float* bl0 = (const float*)d_in[3];
    const float* Wr0 = (const float*)d_in[4];
    const float* Wl1 = (const float*)d_in[5];
    const float* bl1 = (const float*)d_in[6];
    const float* Wr1 = (const float*)d_in[7];
    const float* Wl2 = (const float*)d_in[8];
    const float* bl2 = (const float*)d_in[9];
    const float* Wr2 = (const float*)d_in[10];
    float* out = (float*)d_out;

    const int* srcp = ei;
    const int* dstp = ei + N_EDGES;

    char* ws = (char*)d_ws;
    size_t off = 0;
    auto alloc = [&](size_t bytes) -> void* {
        void* p = ws + off;
        off += (bytes + 255) & ~(size_t)255;
        return p;
    };
    int* gcursor     = (int*)alloc(256 * 4);
    int* bucket_base = (int*)alloc((NBUCK + 1) * 4);
    int* offsets     = (int*)alloc((size_t)(N_NODES + 1) * 4);
    u32* stage       = (u32*)alloc((size_t)NBUCK * BCAP * 4);
    int* ssrc        = (int*)alloc((size_t)N_EDGES * 4);
    u16* wf0         = (u16*)alloc((size_t)192 * 256 * 2);
    u16* wf1         = (u16*)alloc((size_t)128 * 256 * 2);
    u8* ybuf         = (u8*)alloc((size_t)N_NODES * 128);
    u16* rbuf        = (u16*)alloc((size_t)N_NODES * 128 * 2);
    u16* h0          = (u16*)alloc((size_t)N_NODES * 128 * 2);
    float* zbuf      = (float*)alloc((size_t)N_NODES * 2 * 4);
    float* r2buf     = (float*)alloc((size_t)N_NODES * 2 * 4);
    (void)ws_size; (void)n_in; (void)in_sizes; (void)out_size;

    // ---- graph build ----
    k_zero<<<1, 256, 0, stream>>>(gcursor);   // re-zero per launch (determinism)
    const int NB_SC = (N_EDGES / 4 + 1023) / 1024;   // 245
    k_scatter<<<NB_SC, 256, 0, stream>>>(srcp, dstp, gcursor, stage);
    k_bucketscan<<<1, 256, 0, stream>>>(gcursor, bucket_base, offsets);
    k_csr<<<NBUCK, 256, 0, stream>>>(stage, bucket_base, offsets, ssrc);

    // ---- weight conversion ----
    k_wprep<<<(192 / 32) * 16, 64, 0, stream>>>(Wl0, Wr0, IN_CH, wf0);
    k_wprep<<<(128 / 32) * 16, 64, 0, stream>>>(Wl1, Wr1, HID, wf1);

    // ---- layer 0 ----
    k_projmm0<<<NTILE32, 256, 0, stream>>>(x, wf0, bl0, ybuf, rbuf);
    k_aggb<0><<<N_NODES / 16, 256, 0, stream>>>(ybuf, rbuf, offsets, ssrc,
                                                h0, nullptr, nullptr, nullptr,
                                                nullptr, nullptr);

    // ---- layer 1 (+ fused layer-2 projection) ----
    k_projmm1<<<NTILE32, 256, 0, stream>>>(h0, wf1, bl1, ybuf, rbuf);
    k_aggb<1><<<N_NODES / 16, 256, 0, stream>>>(ybuf, rbuf, offsets, ssrc,
                                                nullptr, Wl2, Wr2, bl2,
                                                zbuf, r2buf);

    // ---- layer 2 aggregation ----
    k_agg2<<<(N_NODES + 255) / 256, 256, 0, stream>>>(zbuf, r2buf, offsets, ssrc, out);
}

// Round 17
// 159.127 us; speedup vs baseline: 3.3306x; 1.0041x over previous
//
#include <hip/hip_runtime.h>

#define N_NODES 100000
#define N_EDGES 1000000
#define IN_CH 166
#define HID 128
#define NTILE32 3125   // 100000 / 32 exactly
#define BSHIFT 9
#define NBUCK 196
#define BCAP 5632      // fixed bucket capacity (mean 5120, sd 72)

typedef unsigned char u8;
typedef unsigned short u16;
typedef unsigned int u32;
typedef __attribute__((ext_vector_type(8))) short short8;
typedef __attribute__((ext_vector_type(4))) float f32x4;
typedef __attribute__((ext_vector_type(2))) float f32x2;

static __device__ __forceinline__ u16 f2bf(float f) {
    unsigned u = __float_as_uint(f);
    u += 0x7FFF + ((u >> 16) & 1);   // RNE
    return (u16)(u >> 16);
}
static __device__ __forceinline__ unsigned pk2(float a, float b) {
    return (unsigned)f2bf(a) | ((unsigned)f2bf(b) << 16);
}
static __device__ __forceinline__ float bf_lo(unsigned w) {
    return __uint_as_float(w << 16);
}
static __device__ __forceinline__ float bf_hi(unsigned w) {
    return __uint_as_float(w & 0xFFFF0000u);
}

// ================= graph build =================

__global__ void k_zero(int* __restrict__ p) {
    p[threadIdx.x] = 0;   // 256 >= NBUCK
}

__global__ __launch_bounds__(256) void k_scatter(const int* __restrict__ src,
                                                 const int* __restrict__ dst,
                                                 int* __restrict__ gcursor,
                                                 u32* __restrict__ stage) {
    __shared__ int cnt[NBUCK];
    __shared__ int base[NBUCK];
    const int t = threadIdx.x;
    if (t < NBUCK) cnt[t] = 0;
    __syncthreads();

    int4 s4[4], d4[4];
    bool ok[4];
#pragma unroll
    for (int j = 0; j < 4; ++j) {
        int e4 = blockIdx.x * 1024 + j * 256 + t;
        ok[j] = (e4 < N_EDGES / 4);
        if (ok[j]) {
            s4[j] = ((const int4*)src)[e4];
            d4[j] = ((const int4*)dst)[e4];
            atomicAdd(&cnt[d4[j].x >> BSHIFT], 1);
            atomicAdd(&cnt[d4[j].y >> BSHIFT], 1);
            atomicAdd(&cnt[d4[j].z >> BSHIFT], 1);
            atomicAdd(&cnt[d4[j].w >> BSHIFT], 1);
        }
    }
    __syncthreads();
    if (t < NBUCK && cnt[t] > 0) base[t] = atomicAdd(&gcursor[t], cnt[t]);
    __syncthreads();

#pragma unroll
    for (int j = 0; j < 4; ++j) {
        if (ok[j]) {
            const int ss[4] = {s4[j].x, s4[j].y, s4[j].z, s4[j].w};
            const int dd[4] = {d4[j].x, d4[j].y, d4[j].z, d4[j].w};
#pragma unroll
            for (int q = 0; q < 4; ++q) {
                int b = dd[q] >> BSHIFT;
                int r = atomicSub(&cnt[b], 1) - 1;
                stage[(size_t)b * BCAP + base[b] + r] =
                    ((u32)ss[q] << 9) | (u32)(dd[q] & 511);
            }
        }
    }
}

__global__ __launch_bounds__(256) void k_bucketscan(const int* __restrict__ gcursor,
                                                    int* __restrict__ bucket_base,
                                                    int* __restrict__ offsets) {
    __shared__ int ws[256];
    const int t = threadIdx.x;
    int loc = (t < NBUCK) ? gcursor[t] : 0;
    ws[t] = loc;
    __syncthreads();
    int val = loc;
    for (int stp = 1; stp < 256; stp <<= 1) {
        int other = (t >= stp) ? ws[t - stp] : 0;
        __syncthreads();
        val += other;
        ws[t] = val;
        __syncthreads();
    }
    if (t < NBUCK) bucket_base[t] = val - loc;
    if (t == 255) bucket_base[NBUCK] = val;
    if (t == 0) offsets[N_NODES] = N_EDGES;
}

__global__ __launch_bounds__(256) void k_csr(const u32* __restrict__ stage,
                                             const int* __restrict__ bucket_base,
                                             int* __restrict__ offsets,
                                             int* __restrict__ ssrc) {
    __shared__ int cnt[512];
    __shared__ int ws[256];
    const int t = threadIdx.x;
    const int b = blockIdx.x;
    const int nb0 = b << BSHIFT;
    const int nn = min(512, N_NODES - nb0);
    const size_t e0s = (size_t)b * BCAP;
    const int e0 = bucket_base[b];
    const int m = bucket_base[b + 1] - e0;

    cnt[t] = 0;
    cnt[t + 256] = 0;
    __syncthreads();

    for (int i = t; i < m; i += 256) {
        u32 pr = stage[e0s + i];
        atomicAdd(&cnt[pr & 511], 1);
    }
    __syncthreads();

    int c0 = cnt[2 * t];
    int c1 = cnt[2 * t + 1];
    int loc = c0 + c1;
    ws[t] = loc;
    __syncthreads();
    int val = loc;
    for (int stp = 1; stp < 256; stp <<= 1) {
        int other = (t >= stp) ? ws[t - stp] : 0;
        __syncthreads();
        val += other;
        ws[t] = val;
        __syncthreads();
    }
    int p0 = e0 + (val - loc);
    int p1 = p0 + c0;
    if (2 * t < nn) offsets[nb0 + 2 * t] = p0;
    if (2 * t + 1 < nn) offsets[nb0 + 2 * t + 1] = p1;
    cnt[2 * t] = p0;
    cnt[2 * t + 1] = p1;
    __syncthreads();

    for (int i = t; i < m; i += 256) {
        u32 pr = stage[e0s + i];
        int p = atomicAdd(&cnt[pr & 511], 1);
        ssrc[p] = (int)(pr >> 9);
    }
}

// ---------------- weight prep: Wl|Wr -> bf16 MFMA fragments ----------------

__global__ __launch_bounds__(64) void k_wprep(const float* __restrict__ Wl,
                                              const float* __restrict__ Wr,
                                              int Kact, u16* __restrict__ wf) {
    int lane = threadIdx.x;
    int kt = blockIdx.x >> 4;
    int ct = blockIdx.x & 15;
    int col = ct * 16 + (lane & 15);
    const float* W = (col < 128) ? Wl : Wr;
    int wcol = col & 127;
    float v[8];
#pragma unroll
    for (int j = 0; j < 8; ++j) {
        int row = kt * 32 + (lane >> 4) * 8 + j;
        v[j] = (row < Kact) ? W[(size_t)row * 128 + wcol] : 0.f;
    }
    int4 o;
    o.x = pk2(v[0], v[1]);
    o.y = pk2(v[2], v[3]);
    o.z = pk2(v[4], v[5]);
    o.w = pk2(v[6], v[7]);
    *(int4*)(wf + ((size_t)blockIdx.x * 64 + lane) * 8) = o;
}

// ---------------- MFMA projection, 32-row tiles, 256 threads -------------
// 4 waves; wave = col-group cg (0..3): cols cg*64..+63, all 32 rows.
// swapped operands: lane&15 = node row, (lane>>4)*4+i = output col.
// y fp8 e4m3 (HW cvt); rb bf16. Merged single-barrier-pair epilogue:
// LDS regions: y bytes [0, 4608), rb u16 [2304, 6656).

#define LDS_U16 6656   // 13312 B shared pool
#define STR2 136       // u16 stride, rb region (base u16 2304)
#define STRY 144       // byte stride, y region (base 0)

template <int KP>
static __device__ __forceinline__ void proj_tail(const u16* __restrict__ wf,
                                                 const float* __restrict__ bias,
                                                 u8* __restrict__ y,
                                                 u16* __restrict__ rb,
                                                 u16* sA, int n0) {
    constexpr int STR = KP + 8;
    const int tid = threadIdx.x;
    const int cg = tid >> 6;      // 0..3
    const int lane = tid & 63;
    const int r16 = lane & 15;
    const int kq = lane >> 4;

    f32x4 acc[2][4];
#pragma unroll
    for (int a = 0; a < 2; ++a)
#pragma unroll
        for (int b = 0; b < 4; ++b) acc[a][b] = (f32x4){0.f, 0.f, 0.f, 0.f};

#pragma unroll
    for (int kt = 0; kt < KP / 32; ++kt) {
        short8 af[2], bf[4];
#pragma unroll
        for (int rt = 0; rt < 2; ++rt)
            af[rt] = *(const short8*)(&sA[(rt * 16 + r16) * STR + kt * 32 + kq * 8]);
#pragma unroll
        for (int c = 0; c < 4; ++c)
            bf[c] = *(const short8*)(wf + (((size_t)(kt * 16 + cg * 4 + c) * 64 + lane) * 8));
#pragma unroll
        for (int rt = 0; rt < 2; ++rt)
#pragma unroll
            for (int c = 0; c < 4; ++c)
                acc[rt][c] = __builtin_amdgcn_mfma_f32_16x16x32_bf16(bf[c], af[rt], acc[rt][c], 0, 0, 0);
    }

    // ---- merged epilogue: one barrier pair for both Y and R phases ----
    __syncthreads();   // all waves done reading staging
    u8* sB = (u8*)sA;              // y region: bytes 0..4607
    u16* sR = sA + 2304;           // rb region: u16 2304..6655
    if (cg < 2) {
        // y half: fp8 pack into LDS
#pragma unroll
        for (int rt = 0; rt < 2; ++rt) {
            int row = rt * 16 + r16;
#pragma unroll
            for (int c = 0; c < 4; ++c) {
                int col = cg * 64 + c * 16 + kq * 4;
                int w = __builtin_amdgcn_cvt_pk_fp8_f32(acc[rt][c][0], acc[rt][c][1], 0, false);
                w = __builtin_amdgcn_cvt_pk_fp8_f32(acc[rt][c][2], acc[rt][c][3], w, true);
                *(int*)(&sB[row * STRY + col]) = w;
            }
        }
    } else {
        // r half: bf16 (+bias) into LDS
#pragma unroll
        for (int rt = 0; rt < 2; ++rt) {
            int row = rt * 16 + r16;
#pragma unroll
            for (int c = 0; c < 4; ++c) {
                int col = (cg - 2) * 64 + c * 16 + kq * 4;
                float4 bv = *(const float4*)&bias[col];
                int2 ov;
                ov.x = pk2(acc[rt][c][0] + bv.x, acc[rt][c][1] + bv.y);
                ov.y = pk2(acc[rt][c][2] + bv.z, acc[rt][c][3] + bv.w);
                *(int2*)(&sR[row * STR2 + col]) = ov;
            }
        }
    }
    __syncthreads();
    {   // y store: 32 rows x 8 int4 = 256, one per thread
        int row = tid >> 3;
        int ch = tid & 7;
        int4 v = *(const int4*)(&sB[row * STRY + ch * 16]);
        *(int4*)(y + (size_t)(n0 + row) * 128 + ch * 16) = v;
    }
#pragma unroll
    for (int p = 0; p < 2; ++p) {   // rb store: 32 rows x 16 int4 = 512
        int c = p * 256 + tid;
        int row = c >> 4;
        int ch = c & 15;
        int4 v = *(const int4*)(&sR[row * STR2 + ch * 8]);
        *(int4*)(rb + (size_t)(n0 + row) * 128 + ch * 8) = v;
    }
}

// layer 0: fp32 x [N,166]; 32-row tile = exactly 1328 aligned float4.
// Staging: ALL loads issued to registers first (pipelined), then cvt+LDS.
__global__ __launch_bounds__(256, 8) void k_projmm0(const float* __restrict__ in,
                                                    const u16* __restrict__ wf,
                                                    const float* __restrict__ bias,
                                                    u8* __restrict__ y,
                                                    u16* __restrict__ rb) {
    constexpr int KP = 192;
    constexpr int STR = KP + 8;   // 200
    __shared__ u16 sA[LDS_U16];   // staging uses 32*200 = 6400 u16
    const int tid = threadIdx.x;
    const int n0 = blockIdx.x * 32;

    // phase 1: issue all global loads (no LDS writes in between)
    const float4* x4 = (const float4*)in;
    const size_t gbase = (size_t)blockIdx.x * 1328;
    float4 v[6];
#pragma unroll
    for (int it = 0; it < 5; ++it)
        v[it] = x4[gbase + it * 256 + tid];       // 1280 unconditional
    if (tid < 48)
        v[5] = x4[gbase + 1280 + tid];            // tail to 1328

    // zero-fill K pad cols 166..191: 32 rows x 13 u32 (overlaps load latency)
    for (int c = tid; c < 32 * 13; c += 256) {
        int row = c / 13;
        int col = 166 + (c - row * 13) * 2;
        *(unsigned*)(&sA[row * STR + col]) = 0;
    }

    // phase 2: convert + LDS write
#pragma unroll
    for (int it = 0; it < 6; ++it) {
        if (it == 5 && tid >= 48) break;
        int f = it * 256 + tid;
        int e0 = f * 4;
        int row = e0 / IN_CH;
        int k = e0 - row * IN_CH;
        if (k <= IN_CH - 4) {   // fast path (98.8%)
            *(unsigned*)(&sA[row * STR + k]) = pk2(v[it].x, v[it].y);
            *(unsigned*)(&sA[row * STR + k + 2]) = pk2(v[it].z, v[it].w);
        } else {
            const float vv[4] = {v[it].x, v[it].y, v[it].z, v[it].w};
#pragma unroll
            for (int j = 0; j < 4; ++j) {
                int kk = k + j;
                int r = row, c = kk;
                if (kk >= IN_CH) { r = row + 1; c = kk - IN_CH; }
                if (r < 32) sA[r * STR + c] = f2bf(vv[j]);
            }
        }
    }
    __syncthreads();
    proj_tail<KP>(wf, bias, y, rb, sA, n0);
}

// layer 1: bf16 input [N,128], 32-row tile; loads batched before writes
__global__ __launch_bounds__(256, 8) void k_projmm1(const u16* __restrict__ in,
                                                    const u16* __restrict__ wf,
                                                    const float* __restrict__ bias,
                                                    u8* __restrict__ y,
                                                    u16* __restrict__ rb) {
    constexpr int KP = 128;
    constexpr int STR = KP + 8;   // 136
    __shared__ u16 sA[LDS_U16];   // staging uses 32*136 = 4352 u16
    const int tid = threadIdx.x;
    const int n0 = blockIdx.x * 32;

    int4 v0 = *(const int4*)(in + (size_t)((tid) >> 4) * KP + (size_t)(n0) * KP + (tid & 15) * 8);
    int4 v1 = *(const int4*)(in + (size_t)((256 + tid) >> 4) * KP + (size_t)(n0) * KP + ((256 + tid) & 15) * 8);
    {
        int c0 = tid, c1 = 256 + tid;
        *(int4*)(&sA[(c0 >> 4) * STR + (c0 & 15) * 8]) = v0;
        *(int4*)(&sA[(c1 >> 4) * STR + (c1 & 15) * 8]) = v1;
    }
    __syncthreads();
    proj_tail<KP>(wf, bias, y, rb, sA, n0);
}

// ---------------- aggregation (fp8 gather; optional fused layer-2) ---

static __device__ __forceinline__ void acc_fp8(float* acc, int2 v) {
    f32x2 p;
    p = __builtin_amdgcn_cvt_pk_f32_fp8(v.x, false); acc[0] += p.x; acc[1] += p.y;
    p = __builtin_amdgcn_cvt_pk_f32_fp8(v.x, true);  acc[2] += p.x; acc[3] += p.y;
    p = __builtin_amdgcn_cvt_pk_f32_fp8(v.y, false); acc[4] += p.x; acc[5] += p.y;
    p = __builtin_amdgcn_cvt_pk_f32_fp8(v.y, true);  acc[6] += p.x; acc[7] += p.y;
}

template <int FUSE>
__global__ __launch_bounds__(256) void k_aggb(const u8* __restrict__ yb,
                                              const u16* __restrict__ rb,
                                              const int* __restrict__ offsets,
                                              const int* __restrict__ ssrc,
                                              u16* __restrict__ h,
                                              const float* __restrict__ Wl2,
                                              const float* __restrict__ Wr2,
                                              const float* __restrict__ bl2,
                                              float* __restrict__ z,
                                              float* __restrict__ r2) {
    __shared__ float2 sWl[128];
    __shared__ float2 sWr[128];
    const int tid = threadIdx.x;
    if (FUSE) {
        if (tid < 128) sWl[tid] = ((const float2*)Wl2)[tid];
        else sWr[tid - 128] = ((const float2*)Wr2)[tid - 128];
        __syncthreads();
    }
    const int lane = tid & 63;
    const int wv = tid >> 6;
    const int g = lane >> 4;
    const int i = lane & 15;
    const int node = blockIdx.x * 16 + wv * 4 + g;
    const int off0 = offsets[node];
    const int deg = offsets[node + 1] - off0;

    float acc[8] = {0.f, 0.f, 0.f, 0.f, 0.f, 0.f, 0.f, 0.f};

    int e = 0;
    for (; e + 3 < deg; e += 4) {
        int s0 = ssrc[off0 + e];
        int s1 = ssrc[off0 + e + 1];
        int s2 = ssrc[off0 + e + 2];
        int s3 = ssrc[off0 + e + 3];
        int2 v0 = *(const int2*)(yb + (size_t)s0 * 128 + i * 8);
        int2 v1 = *(const int2*)(yb + (size_t)s1 * 128 + i * 8);
        int2 v2 = *(const int2*)(yb + (size_t)s2 * 128 + i * 8);
        int2 v3 = *(const int2*)(yb + (size_t)s3 * 128 + i * 8);
        acc_fp8(acc, v0);
        acc_fp8(acc, v1);
        acc_fp8(acc, v2);
        acc_fp8(acc, v3);
    }
    for (; e < deg; ++e) {
        int s0 = ssrc[off0 + e];
        int2 v0 = *(const int2*)(yb + (size_t)s0 * 128 + i * 8);
        acc_fp8(acc, v0);
    }

    float inv = 1.f / (float)max(deg, 1);
    int4 rv = *(const int4*)(rb + (size_t)node * 128 + i * 8);
    const unsigned* rw = (const unsigned*)&rv;
    float o[8];
#pragma unroll
    for (int q = 0; q < 4; ++q) {
        o[q * 2]     = fmaxf(acc[q * 2] * inv + bf_lo(rw[q]), 0.f);
        o[q * 2 + 1] = fmaxf(acc[q * 2 + 1] * inv + bf_hi(rw[q]), 0.f);
    }

    if (!FUSE) {
        int4 ov;
        ov.x = pk2(o[0], o[1]);
        ov.y = pk2(o[2], o[3]);
        ov.z = pk2(o[4], o[5]);
        ov.w = pk2(o[6], o[7]);
        *(int4*)(h + (size_t)node * 128 + i * 8) = ov;
    } else {
        float zl0 = 0.f, zl1 = 0.f, zr0 = 0.f, zr1 = 0.f;
#pragma unroll
        for (int j = 0; j < 8; ++j) {
            float2 wl = sWl[i * 8 + j];
            float2 wr = sWr[i * 8 + j];
            zl0 += o[j] * wl.x;
            zl1 += o[j] * wl.y;
            zr0 += o[j] * wr.x;
            zr1 += o[j] * wr.y;
        }
#pragma unroll
        for (int d = 1; d < 16; d <<= 1) {
            zl0 += __shfl_xor(zl0, d);
            zl1 += __shfl_xor(zl1, d);
            zr0 += __shfl_xor(zr0, d);
            zr1 += __shfl_xor(zr1, d);
        }
        if (i == 0) {
            float2 zv; zv.x = zl0; zv.y = zl1;
            float2 rv2; rv2.x = zr0 + bl2[0]; rv2.y = zr1 + bl2[1];
            *(float2*)(z + (size_t)node * 2) = zv;
            *(float2*)(r2 + (size_t)node * 2) = rv2;
        }
    }
}

// ---------------- layer 2 aggregation (2 channels) ----------------

__global__ __launch_bounds__(256) void k_agg2(const float* __restrict__ z,
                                              const float* __restrict__ r2,
                                              const int* __restrict__ offsets,
                                              const int* __restrict__ ssrc,
                                              float* __restrict__ out) {
    int n = blockIdx.x * 256 + threadIdx.x;
    if (n >= N_NODES) return;
    int off0 = offsets[n];
    int off1 = offsets[n + 1];
    float a0 = 0.f, a1 = 0.f;
    const float2* z2 = (const float2*)z;
    for (int e = off0; e < off1; ++e) {
        float2 v = z2[ssrc[e]];
        a0 += v.x;
        a1 += v.y;
    }
    float inv = 1.0f / (float)max(off1 - off0, 1);
    float2 rv = ((const float2*)r2)[n];
    float2 ov;
    ov.x = a0 * inv + rv.x;
    ov.y = a1 * inv + rv.y;
    ((float2*)out)[n] = ov;
}

// ---------------- launcher ----------------

extern "C" void kernel_launch(void* const* d_in, const int* in_sizes, int n_in,
                              void* d_out, int out_size, void* d_ws, size_t ws_size,
                              hipStream_t stream) {
    const float* x   = (const float*)d_in[0];
    const int*   ei  = (const int*)d_in[1];
    const float* Wl0 = (const float*)d_in[2];
    const float* bl0 = (const float*)d_in[3];
    const float* Wr0 = (const float*)d_in[4];
    const float* Wl1 = (const float*)d_in[5];
    const float* bl1 = (const float*)d_in[6];
    const float* Wr1 = (const float*)d_in[7];
    const float* Wl2 = (const float*)d_in[8];
    const float* bl2 = (const float*)d_in[9];
    const float* Wr2 = (const float*)d_in[10];
    float* out = (float*)d_out;

    const int* srcp = ei;
    const int* dstp = ei + N_EDGES;

    char* ws = (char*)d_ws;
    size_t off = 0;
    auto alloc = [&](size_t bytes) -> void* {
        void* p = ws + off;
        off += (bytes + 255) & ~(size_t)255;
        return p;
    };
    int* gcursor     = (int*)alloc(256 * 4);
    int* bucket_base = (int*)alloc((NBUCK + 1) * 4);
    int* offsets     = (int*)alloc((size_t)(N_NODES + 1) * 4);
    u32* stage       = (u32*)alloc((size_t)NBUCK * BCAP * 4);
    int* ssrc        = (int*)alloc((size_t)N_EDGES * 4);
    u16* wf0         = (u16*)alloc((size_t)192 * 256 * 2);
    u16* wf1         = (u16*)alloc((size_t)128 * 256 * 2);
    u8* ybuf         = (u8*)alloc((size_t)N_NODES * 128);
    u16* rbuf        = (u16*)alloc((size_t)N_NODES * 128 * 2);
    u16* h0          = (u16*)alloc((size_t)N_NODES * 128 * 2);
    float* zbuf      = (float*)alloc((size_t)N_NODES * 2 * 4);
    float* r2buf     = (float*)alloc((size_t)N_NODES * 2 * 4);
    (void)ws_size; (void)n_in; (void)in_sizes; (void)out_size;

    // ---- graph build ----
    k_zero<<<1, 256, 0, stream>>>(gcursor);   // re-zero per launch (determinism)
    const int NB_SC = (N_EDGES / 4 + 1023) / 1024;   // 245
    k_scatter<<<NB_SC, 256, 0, stream>>>(srcp, dstp, gcursor, stage);
    k_bucketscan<<<1, 256, 0, stream>>>(gcursor, bucket_base, offsets);
    k_csr<<<NBUCK, 256, 0, stream>>>(stage, bucket_base, offsets, ssrc);

    // ---- weight conversion ----
    k_wprep<<<(192 / 32) * 16, 64, 0, stream>>>(Wl0, Wr0, IN_CH, wf0);
    k_wprep<<<(128 / 32) * 16, 64, 0, stream>>>(Wl1, Wr1, HID, wf1);

    // ---- layer 0 ----
    k_projmm0<<<NTILE32, 256, 0, stream>>>(x, wf0, bl0, ybuf, rbuf);
    k_aggb<0><<<N_NODES / 16, 256, 0, stream>>>(ybuf, rbuf, offsets, ssrc,
                                                h0, nullptr, nullptr, nullptr,
                                                nullptr, nullptr);

    // ---- layer 1 (+ fused layer-2 projection) ----
    k_projmm1<<<NTILE32, 256, 0, stream>>>(h0, wf1, bl1, ybuf, rbuf);
    k_aggb<1><<<N_NODES / 16, 256, 0, stream>>>(ybuf, rbuf, offsets, ssrc,
                                                nullptr, Wl2, Wr2, bl2,
                                                zbuf, r2buf);

    // ---- layer 2 aggregation ----
    k_agg2<<<(N_NODES + 255) / 256, 256, 0, stream>>>(zbuf, r2buf, offsets, ssrc, out);
}